// Round 1
// baseline (516.675 us; speedup 1.0000x reference)
//
#include <hip/hip_runtime.h>
#include <stdint.h>

#define BB   64
#define QQ   1000
#define CC   1203
#define NROW (QQ*CC)         // 1203000
#define NROW4 (NROW/4)       // 300750
#define KSEL 1000
#define TOPKN 100
#define NBINS 8192
#define CAPN 4096

// workspace byte offsets
#define WS_HIST 0
#define WS_TSTAR (BB*NBINS*4)              // 2097152
#define WS_CNT   (WS_TSTAR + 256)          // 2097408
#define WS_CAND  (WS_CNT + 256)            // 2097664 (8B aligned)
#define WS_QSEL  (WS_CAND + (size_t)BB*CAPN*8)   // 4194816
#define WS_ZERO_BYTES WS_CAND

// output float offsets (return-order concat)
#define O_SCORES 0
#define O_LABELS (BB*TOPKN)                  // 6400
#define O_BOXES  (2*BB*TOPKN)                // 12800
#define O_PROB   (O_BOXES + BB*TOPKN*4)      // 38400
#define O_TIA    (O_PROB + (size_t)BB*TOPKN*CC)  // 7737600
#define O_BNORM  (O_TIA + BB*KSEL)               // 7801600

__device__ __forceinline__ uint32_t fkey(float f) {
    uint32_t x = __float_as_uint(f);
    return x ^ ((x & 0x80000000u) ? 0xFFFFFFFFu : 0x80000000u);
}
__device__ __forceinline__ float finv(uint32_t u) {
    uint32_t x = (u & 0x80000000u) ? (u ^ 0x80000000u) : ~u;
    return __uint_as_float(x);
}
__device__ __forceinline__ float sigmoidf_(float x) {
    if (x >= 0.0f) { float e = expf(-x); return 1.0f / (1.0f + e); }
    float e = expf(x); return e / (1.0f + e);
}

// ---------------- pass 1: per-row histogram of top-13-bit keys ----------------
__global__ void __launch_bounds__(256) k_hist(const float4* __restrict__ lg4,
                                              uint32_t* __restrict__ hist) {
    __shared__ uint32_t h[NBINS];
    const int b = blockIdx.y;
    for (int i = threadIdx.x; i < NBINS; i += blockDim.x) h[i] = 0;
    __syncthreads();
    const float4* row = lg4 + (size_t)b * NROW4;
    const int stride = blockDim.x * gridDim.x;
    for (int i = blockIdx.x * blockDim.x + threadIdx.x; i < NROW4; i += stride) {
        float4 v = row[i];
        atomicAdd(&h[fkey(v.x) >> 19], 1u);
        atomicAdd(&h[fkey(v.y) >> 19], 1u);
        atomicAdd(&h[fkey(v.z) >> 19], 1u);
        atomicAdd(&h[fkey(v.w) >> 19], 1u);
    }
    __syncthreads();
    uint32_t* gh = hist + (size_t)b * NBINS;
    for (int i = threadIdx.x; i < NBINS; i += blockDim.x) {
        uint32_t c = h[i];
        if (c) atomicAdd(&gh[i], c);
    }
}

// ---------------- pass 2: find threshold bin t* per row ----------------
__global__ void __launch_bounds__(1024) k_findbin(const uint32_t* __restrict__ hist,
                                                  uint32_t* __restrict__ tstar) {
    __shared__ uint32_t part[1024];
    const int b = blockIdx.x;
    const uint32_t* gh = hist + (size_t)b * NBINS;
    const int tid = threadIdx.x;
    const int base = tid * 8;
    uint32_t s = 0;
#pragma unroll
    for (int k = 0; k < 8; ++k) s += gh[base + k];
    part[tid] = s;
    __syncthreads();
    // suffix-inclusive scan: part[c] = sum_{j>=c} part_orig[j]
    for (int off = 1; off < 1024; off <<= 1) {
        uint32_t v = part[tid];
        uint32_t add = (tid + off < 1024) ? part[tid + off] : 0u;
        __syncthreads();
        part[tid] = v + add;
        __syncthreads();
    }
    // unique chunk where S(8c) >= K and S(8(c+1)) < K
    if (part[tid] >= KSEL && (tid == 1023 || part[tid + 1] < KSEL)) {
        uint32_t ssum = (tid == 1023) ? 0u : part[tid + 1];
        uint32_t t = (uint32_t)base;
        for (int k = 7; k >= 0; --k) {
            ssum += gh[base + k];
            if (ssum >= KSEL) { t = (uint32_t)(base + k); break; }
        }
        tstar[b] = t;
    }
}

// ---------------- pass 3: collect candidates >= threshold bin ----------------
__global__ void __launch_bounds__(256) k_collect(const float4* __restrict__ lg4,
                                                 const uint32_t* __restrict__ tstar,
                                                 uint32_t* __restrict__ cnt,
                                                 uint64_t* __restrict__ cand) {
    const int b = blockIdx.y;
    const uint32_t ts = tstar[b];
    const float4* row = lg4 + (size_t)b * NROW4;
    uint32_t* pc = cnt + b;
    uint64_t* pcand = cand + (size_t)b * CAPN;
    const int stride = blockDim.x * gridDim.x;
    for (int i = blockIdx.x * blockDim.x + threadIdx.x; i < NROW4; i += stride) {
        float4 v = row[i];
        float c4[4] = {v.x, v.y, v.z, v.w};
#pragma unroll
        for (int j = 0; j < 4; ++j) {
            uint32_t u = fkey(c4[j]);
            if ((u >> 19) >= ts) {
                uint32_t pos = atomicAdd(pc, 1u);
                if (pos < CAPN) {
                    uint32_t idx = (uint32_t)(i * 4 + j);
                    pcand[pos] = ((uint64_t)u << 32) | (uint32_t)(~idx);
                }
            }
        }
    }
}

// ---------------- pass 4: per-row bitonic sort + main outputs ----------------
__global__ void __launch_bounds__(1024) k_sortout(const uint32_t* __restrict__ cnt,
                                                  const uint64_t* __restrict__ cand,
                                                  const float4* __restrict__ pb4,
                                                  const float* __restrict__ tsz,
                                                  float* __restrict__ out,
                                                  int* __restrict__ qsel) {
    __shared__ uint64_t s[CAPN];
    const int b = blockIdx.x;
    const int tid = threadIdx.x;
    uint32_t n = cnt[b];
    if (n > CAPN) n = CAPN;
    const uint64_t* pcand = cand + (size_t)b * CAPN;
    for (int i = tid; i < CAPN; i += 1024) s[i] = (i < (int)n) ? pcand[i] : 0ull;
    __syncthreads();
    // bitonic sort, descending by composite (key desc, idx asc on ties)
    for (unsigned k = 2; k <= CAPN; k <<= 1) {
        for (unsigned j = k >> 1; j > 0; j >>= 1) {
#pragma unroll
            for (unsigned base = 0; base < CAPN; base += 1024) {
                unsigned i = base + tid;
                unsigned ixj = i ^ j;
                if (ixj > i) {
                    uint64_t a = s[i], c = s[ixj];
                    bool up = ((i & k) == 0);
                    if (up ? (a < c) : (a > c)) { s[i] = c; s[ixj] = a; }
                }
            }
            __syncthreads();
        }
    }
    // top-1000: topk_indexes_all
    for (int jj = tid; jj < KSEL; jj += 1024) {
        uint64_t c = s[jj];
        uint32_t idx = ~((uint32_t)c);
        uint32_t q = idx / (uint32_t)CC;
        out[O_TIA + b * KSEL + jj] = (float)q;
    }
    // top-100: scores, labels, boxes, boxes_norm, qsel
    if (tid < TOPKN) {
        uint64_t c = s[tid];
        uint32_t u = (uint32_t)(c >> 32);
        uint32_t idx = ~((uint32_t)c);
        uint32_t q = idx / (uint32_t)CC;
        uint32_t lab = idx - q * (uint32_t)CC;
        float logit = finv(u);
        out[O_SCORES + b * TOPKN + tid] = sigmoidf_(logit);
        out[O_LABELS + b * TOPKN + tid] = (float)lab;
        qsel[b * TOPKN + tid] = (int)q;
        float4 pb = pb4[b * QQ + q];
        float x0 = pb.x - 0.5f * pb.z;
        float y0 = pb.y - 0.5f * pb.w;
        float x1 = pb.x + 0.5f * pb.z;
        float y1 = pb.y + 0.5f * pb.w;
        float ih = tsz[b * 2 + 0];
        float iw = tsz[b * 2 + 1];
        float4* obn = (float4*)(out + O_BNORM);
        float4* obx = (float4*)(out + O_BOXES);
        obn[b * TOPKN + tid] = make_float4(x0, y0, x1, y1);
        obx[b * TOPKN + tid] = make_float4(x0 * iw, y0 * ih, x1 * iw, y1 * ih);
    }
}

// ---------------- pass 5: topk_inst_prob gather + sigmoid ----------------
__global__ void __launch_bounds__(256) k_prob(const float* __restrict__ lg,
                                              const int* __restrict__ qsel,
                                              float* __restrict__ out) {
    const int r = blockIdx.x;          // 0..B*TOPK
    const int b = r / TOPKN;
    const int q = qsel[r];
    const float* src = lg + ((size_t)b * QQ + q) * CC;
    float* dst = out + O_PROB + (size_t)r * CC;
    for (int c = threadIdx.x; c < CC; c += 256) dst[c] = sigmoidf_(src[c]);
}

extern "C" void kernel_launch(void* const* d_in, const int* in_sizes, int n_in,
                              void* d_out, int out_size, void* d_ws, size_t ws_size,
                              hipStream_t stream) {
    const float* logits = (const float*)d_in[0];
    const float* boxes  = (const float*)d_in[1];
    const float* tsz    = (const float*)d_in[2];
    float* out = (float*)d_out;
    uint8_t* ws = (uint8_t*)d_ws;

    uint32_t* hist  = (uint32_t*)(ws + WS_HIST);
    uint32_t* tstar = (uint32_t*)(ws + WS_TSTAR);
    uint32_t* cnt   = (uint32_t*)(ws + WS_CNT);
    uint64_t* cand  = (uint64_t*)(ws + WS_CAND);
    int*      qsel  = (int*)(ws + WS_QSEL);

    hipMemsetAsync(d_ws, 0, WS_ZERO_BYTES, stream);

    dim3 g1(38, BB);
    k_hist<<<g1, 256, 0, stream>>>((const float4*)logits, hist);
    k_findbin<<<BB, 1024, 0, stream>>>(hist, tstar);
    k_collect<<<g1, 256, 0, stream>>>((const float4*)logits, tstar, cnt, cand);
    k_sortout<<<BB, 1024, 0, stream>>>(cnt, cand, (const float4*)boxes, tsz, out, qsel);
    k_prob<<<BB * TOPKN, 256, 0, stream>>>(logits, qsel, out);
}

// Round 2
// 196.402 us; speedup vs baseline: 2.6307x; 2.6307x over previous
//
#include <hip/hip_runtime.h>
#include <stdint.h>

#define BB   64
#define QQ   1000
#define CC   1203
#define NROW (QQ*CC)         // 1203000
#define NROW4 (NROW/4)       // 300750
#define KSEL 1000
#define TOPKN 100
#define NBINS 8192
#define CAPN 4096
#define LCAP 2048
#define GRIDX 38

// workspace byte offsets
#define WS_HIST 0
#define WS_TSTAR (BB*NBINS*4)              // 2097152
#define WS_CNT   (WS_TSTAR + 256)          // 2097408
#define WS_CAND  (WS_CNT + 256)            // 2097664 (8B aligned)
#define WS_QSEL  (WS_CAND + (size_t)BB*CAPN*8)   // 4194816
#define WS_ZERO_BYTES WS_CAND

// output float offsets (return-order concat)
#define O_SCORES 0
#define O_LABELS (BB*TOPKN)                  // 6400
#define O_BOXES  (2*BB*TOPKN)                // 12800
#define O_PROB   (O_BOXES + BB*TOPKN*4)      // 38400
#define O_TIA    (O_PROB + (size_t)BB*TOPKN*CC)  // 7737600
#define O_BNORM  (O_TIA + BB*KSEL)               // 7801600

__device__ __forceinline__ uint32_t fkey(float f) {
    uint32_t x = __float_as_uint(f);
    return x ^ ((x & 0x80000000u) ? 0xFFFFFFFFu : 0x80000000u);
}
__device__ __forceinline__ float finv(uint32_t u) {
    uint32_t x = (u & 0x80000000u) ? (u ^ 0x80000000u) : ~u;
    return __uint_as_float(x);
}
__device__ __forceinline__ float sigmoidf_(float x) {
    if (x >= 0.0f) { float e = expf(-x); return 1.0f / (1.0f + e); }
    float e = expf(x); return e / (1.0f + e);
}

// ---------------- pass 1: per-row histogram; flush only bins >= local top-K bin --------
__global__ void __launch_bounds__(256) k_hist(const float4* __restrict__ lg4,
                                              uint32_t* __restrict__ hist) {
    __shared__ uint32_t h[NBINS];
    __shared__ uint32_t csum[256];
    __shared__ int s_bl;
    const int b = blockIdx.y;
    const int tid = threadIdx.x;
    for (int i = tid; i < NBINS; i += 256) h[i] = 0;
    if (tid == 0) s_bl = 0;
    __syncthreads();
    const float4* row = lg4 + (size_t)b * NROW4;
    const int stride = 256 * gridDim.x;
    for (int i = blockIdx.x * 256 + tid; i < NROW4; i += stride) {
        float4 v = row[i];
        atomicAdd(&h[fkey(v.x) >> 19], 1u);
        atomicAdd(&h[fkey(v.y) >> 19], 1u);
        atomicAdd(&h[fkey(v.z) >> 19], 1u);
        atomicAdd(&h[fkey(v.w) >> 19], 1u);
    }
    __syncthreads();
    // block-local suffix scan over 256 chunks of 32 bins
    const int base = tid * 32;
    uint32_t s = 0;
#pragma unroll
    for (int k = 0; k < 32; ++k) s += h[base + k];
    csum[tid] = s;
    __syncthreads();
    for (int off = 1; off < 256; off <<= 1) {
        uint32_t v = csum[tid];
        uint32_t a = (tid + off < 256) ? csum[tid + off] : 0u;
        __syncthreads();
        csum[tid] = v + a;
        __syncthreads();
    }
    // chunk where suffix crosses KSEL, then bin-level local threshold bl
    if (csum[tid] >= KSEL && (tid == 255 || csum[tid + 1] < KSEL)) {
        uint32_t ssum = (tid == 255) ? 0u : csum[tid + 1];
        int bl = base;
        for (int k = 31; k >= 0; --k) {
            ssum += h[base + k];
            if (ssum >= KSEL) { bl = base + k; break; }
        }
        s_bl = bl;
    }
    __syncthreads();
    const int bl = s_bl;
    uint32_t* gh = hist + (size_t)b * NBINS;
    for (int i = bl + tid; i < NBINS; i += 256) {
        uint32_t c = h[i];
        if (c) atomicAdd(&gh[i], c);
    }
}

// ---------------- pass 2: find threshold bin t* per row ----------------
__global__ void __launch_bounds__(1024) k_findbin(const uint32_t* __restrict__ hist,
                                                  uint32_t* __restrict__ tstar) {
    __shared__ uint32_t part[1024];
    const int b = blockIdx.x;
    const uint32_t* gh = hist + (size_t)b * NBINS;
    const int tid = threadIdx.x;
    const int base = tid * 8;
    uint32_t s = 0;
#pragma unroll
    for (int k = 0; k < 8; ++k) s += gh[base + k];
    part[tid] = s;
    __syncthreads();
    for (int off = 1; off < 1024; off <<= 1) {
        uint32_t v = part[tid];
        uint32_t add = (tid + off < 1024) ? part[tid + off] : 0u;
        __syncthreads();
        part[tid] = v + add;
        __syncthreads();
    }
    if (part[tid] >= KSEL && (tid == 1023 || part[tid + 1] < KSEL)) {
        uint32_t ssum = (tid == 1023) ? 0u : part[tid + 1];
        uint32_t t = (uint32_t)base;
        for (int k = 7; k >= 0; --k) {
            ssum += gh[base + k];
            if (ssum >= KSEL) { t = (uint32_t)(base + k); break; }
        }
        tstar[b] = t;
    }
}

// ---------------- pass 3: collect candidates, LDS-staged, reverse sweep ----------------
__global__ void __launch_bounds__(256) k_collect(const float4* __restrict__ lg4,
                                                 const uint32_t* __restrict__ tstar,
                                                 uint32_t* __restrict__ cnt,
                                                 uint64_t* __restrict__ cand) {
    __shared__ uint64_t lbuf[LCAP];
    __shared__ uint32_t lcnt, lbase;
    const int b = blockIdx.y;
    const uint32_t ts = tstar[b];
    const int tid = threadIdx.x;
    if (tid == 0) lcnt = 0;
    __syncthreads();
    const float4* row = lg4 + (size_t)b * NROW4;
    uint32_t* pc = cnt + b;
    uint64_t* pcand = cand + (size_t)b * CAPN;
    const int stride = 256 * gridDim.x;
    for (int i0 = blockIdx.x * 256 + tid; i0 < NROW4; i0 += stride) {
        const int i = NROW4 - 1 - i0;            // tail-first: hit L3 leftovers from k_hist
        float4 v = row[i];
        float c4[4] = {v.x, v.y, v.z, v.w};
#pragma unroll
        for (int j = 0; j < 4; ++j) {
            uint32_t u = fkey(c4[j]);
            if ((u >> 19) >= ts) {
                uint64_t pk = ((uint64_t)u << 32) | (uint32_t)(~(uint32_t)(i * 4 + j));
                uint32_t pos = atomicAdd(&lcnt, 1u);
                if (pos < LCAP) lbuf[pos] = pk;
                else { uint32_t g = atomicAdd(pc, 1u); if (g < CAPN) pcand[g] = pk; }
            }
        }
    }
    __syncthreads();
    uint32_t n = lcnt; if (n > LCAP) n = LCAP;
    if (tid == 0) lbase = atomicAdd(pc, n);
    __syncthreads();
    const uint32_t basep = lbase;
    for (uint32_t i2 = tid; i2 < n; i2 += 256) {
        uint32_t g = basep + i2;
        if (g < CAPN) pcand[g] = lbuf[i2];
    }
}

// ---------------- pass 4: per-row bitonic sort + main outputs ----------------
__global__ void __launch_bounds__(1024) k_sortout(const uint32_t* __restrict__ cnt,
                                                  const uint64_t* __restrict__ cand,
                                                  const float4* __restrict__ pb4,
                                                  const float* __restrict__ tsz,
                                                  float* __restrict__ out,
                                                  int* __restrict__ qsel) {
    __shared__ uint64_t s[CAPN];
    const int b = blockIdx.x;
    const int tid = threadIdx.x;
    uint32_t n = cnt[b];
    if (n > CAPN) n = CAPN;
    const unsigned cap = (n <= 2048u) ? 2048u : 4096u;
    const uint64_t* pcand = cand + (size_t)b * CAPN;
    for (unsigned i = tid; i < cap; i += 1024) s[i] = (i < n) ? pcand[i] : 0ull;
    __syncthreads();
    // bitonic sort, descending by composite (key desc, idx asc on ties)
    for (unsigned k = 2; k <= cap; k <<= 1) {
        for (unsigned j = k >> 1; j > 0; j >>= 1) {
            for (unsigned base = 0; base < cap; base += 1024) {
                unsigned i = base + tid;
                unsigned ixj = i ^ j;
                if (ixj > i) {
                    uint64_t a = s[i], c = s[ixj];
                    bool up = ((i & k) == 0);
                    if (up ? (a < c) : (a > c)) { s[i] = c; s[ixj] = a; }
                }
            }
            __syncthreads();
        }
    }
    // top-1000: topk_indexes_all
    for (int jj = tid; jj < KSEL; jj += 1024) {
        uint64_t c = s[jj];
        uint32_t idx = ~((uint32_t)c);
        uint32_t q = idx / (uint32_t)CC;
        out[O_TIA + b * KSEL + jj] = (float)q;
    }
    // top-100: scores, labels, boxes, boxes_norm, qsel
    if (tid < TOPKN) {
        uint64_t c = s[tid];
        uint32_t u = (uint32_t)(c >> 32);
        uint32_t idx = ~((uint32_t)c);
        uint32_t q = idx / (uint32_t)CC;
        uint32_t lab = idx - q * (uint32_t)CC;
        float logit = finv(u);
        out[O_SCORES + b * TOPKN + tid] = sigmoidf_(logit);
        out[O_LABELS + b * TOPKN + tid] = (float)lab;
        qsel[b * TOPKN + tid] = (int)q;
        float4 pb = pb4[b * QQ + q];
        float x0 = pb.x - 0.5f * pb.z;
        float y0 = pb.y - 0.5f * pb.w;
        float x1 = pb.x + 0.5f * pb.z;
        float y1 = pb.y + 0.5f * pb.w;
        float ih = tsz[b * 2 + 0];
        float iw = tsz[b * 2 + 1];
        float4* obn = (float4*)(out + O_BNORM);
        float4* obx = (float4*)(out + O_BOXES);
        obn[b * TOPKN + tid] = make_float4(x0, y0, x1, y1);
        obx[b * TOPKN + tid] = make_float4(x0 * iw, y0 * ih, x1 * iw, y1 * ih);
    }
}

// ---------------- pass 5: topk_inst_prob gather + sigmoid ----------------
__global__ void __launch_bounds__(256) k_prob(const float* __restrict__ lg,
                                              const int* __restrict__ qsel,
                                              float* __restrict__ out) {
    const int r = blockIdx.x;          // 0..B*TOPK
    const int b = r / TOPKN;
    const int q = qsel[r];
    const float* src = lg + ((size_t)b * QQ + q) * CC;
    float* dst = out + O_PROB + (size_t)r * CC;
    for (int c = threadIdx.x; c < CC; c += 256) dst[c] = sigmoidf_(src[c]);
}

extern "C" void kernel_launch(void* const* d_in, const int* in_sizes, int n_in,
                              void* d_out, int out_size, void* d_ws, size_t ws_size,
                              hipStream_t stream) {
    const float* logits = (const float*)d_in[0];
    const float* boxes  = (const float*)d_in[1];
    const float* tsz    = (const float*)d_in[2];
    float* out = (float*)d_out;
    uint8_t* ws = (uint8_t*)d_ws;

    uint32_t* hist  = (uint32_t*)(ws + WS_HIST);
    uint32_t* tstar = (uint32_t*)(ws + WS_TSTAR);
    uint32_t* cnt   = (uint32_t*)(ws + WS_CNT);
    uint64_t* cand  = (uint64_t*)(ws + WS_CAND);
    int*      qsel  = (int*)(ws + WS_QSEL);

    hipMemsetAsync(d_ws, 0, WS_ZERO_BYTES, stream);

    dim3 g1(GRIDX, BB);
    k_hist<<<g1, 256, 0, stream>>>((const float4*)logits, hist);
    k_findbin<<<BB, 1024, 0, stream>>>(hist, tstar);
    k_collect<<<g1, 256, 0, stream>>>((const float4*)logits, tstar, cnt, cand);
    k_sortout<<<BB, 1024, 0, stream>>>(cnt, cand, (const float4*)boxes, tsz, out, qsel);
    k_prob<<<BB * TOPKN, 256, 0, stream>>>(logits, qsel, out);
}

// Round 3
// 126.373 us; speedup vs baseline: 4.0885x; 1.5541x over previous
//
#include <hip/hip_runtime.h>
#include <stdint.h>

#define BB   64
#define QQ   1000
#define CC   1203
#define NROW (QQ*CC)         // 1203000
#define NROW4 (NROW/4)       // 300750
#define KSEL 1000
#define TOPKN 100
#define NBINS 8192
#define CAPN 4096
#define LCAP 2048
#define SBUF 512
#define GRIDX 38
#define FBX 8
#define SPEC_VAL 3.0f        // speculative logit threshold: E[count]=1624/row, 15 sigma > 1000, 10 sigma < 2048

// workspace byte offsets
#define WS_HIST 0
#define WS_TSTAR (BB*NBINS*4)                    // 2097152
#define WS_CNT   (WS_TSTAR + 256)                // 2097408
#define WS_CNTFB (WS_CNT + 256)                  // 2097664
#define WS_CAND  (WS_CNTFB + 256)                // 2097920 (8B aligned)
#define WS_QSEL  (WS_CAND + (size_t)BB*CAPN*8)   // 4195072
#define WS_ZERO_BYTES WS_CAND

// output float offsets (return-order concat)
#define O_SCORES 0
#define O_LABELS (BB*TOPKN)                  // 6400
#define O_BOXES  (2*BB*TOPKN)                // 12800
#define O_PROB   (O_BOXES + BB*TOPKN*4)      // 38400
#define O_TIA    (O_PROB + (size_t)BB*TOPKN*CC)  // 7737600
#define O_BNORM  (O_TIA + BB*KSEL)               // 7801600

__device__ __forceinline__ uint32_t fkey(float f) {
    uint32_t x = __float_as_uint(f);
    return x ^ ((x & 0x80000000u) ? 0xFFFFFFFFu : 0x80000000u);
}
__device__ __forceinline__ float finv(uint32_t u) {
    uint32_t x = (u & 0x80000000u) ? (u ^ 0x80000000u) : ~u;
    return __uint_as_float(x);
}
__device__ __forceinline__ float sigmoidf_(float x) {
    if (x >= 0.0f) { float e = expf(-x); return 1.0f / (1.0f + e); }
    float e = expf(x); return e / (1.0f + e);
}
__device__ __forceinline__ bool row_valid(uint32_t c) {
    return c >= (uint32_t)KSEL && c <= (uint32_t)CAPN;
}

// ---------------- fast path: single-pass speculative stash ----------------
__global__ void __launch_bounds__(256) k_stash(const float4* __restrict__ lg4,
                                               uint32_t* __restrict__ cnt,
                                               uint64_t* __restrict__ cand) {
    __shared__ uint64_t lbuf[SBUF];
    __shared__ uint32_t lcnt, lbase;
    const int b = blockIdx.y;
    const int tid = threadIdx.x;
    if (tid == 0) lcnt = 0;
    __syncthreads();
    const float4* row = lg4 + (size_t)b * NROW4;
    uint32_t* pc = cnt + b;
    uint64_t* pcand = cand + (size_t)b * CAPN;
    const int stride = 256 * gridDim.x;
    for (int i = blockIdx.x * 256 + tid; i < NROW4; i += stride) {
        float4 v = row[i];
        float c4[4] = {v.x, v.y, v.z, v.w};
#pragma unroll
        for (int j = 0; j < 4; ++j) {
            if (c4[j] >= SPEC_VAL) {
                uint64_t pk = ((uint64_t)fkey(c4[j]) << 32) | (uint32_t)(~(uint32_t)(i * 4 + j));
                uint32_t pos = atomicAdd(&lcnt, 1u);
                if (pos < SBUF) lbuf[pos] = pk;
                else { uint32_t g = atomicAdd(pc, 1u); if (g < CAPN) pcand[g] = pk; }
            }
        }
    }
    __syncthreads();
    uint32_t n = lcnt; if (n > SBUF) n = SBUF;
    if (tid == 0) lbase = atomicAdd(pc, n);
    __syncthreads();
    const uint32_t basep = lbase;
    for (uint32_t i2 = tid; i2 < n; i2 += 256) {
        uint32_t g = basep + i2;
        if (g < CAPN) pcand[g] = lbuf[i2];
    }
}

// ---------------- fallback pass 1: per-row histogram (early-exit when stash valid) ----
__global__ void __launch_bounds__(256) k_hist(const float4* __restrict__ lg4,
                                              const uint32_t* __restrict__ cnt,
                                              uint32_t* __restrict__ hist) {
    const int b = blockIdx.y;
    if (row_valid(cnt[b])) return;
    __shared__ uint32_t h[NBINS];
    __shared__ uint32_t csum[256];
    __shared__ int s_bl;
    const int tid = threadIdx.x;
    for (int i = tid; i < NBINS; i += 256) h[i] = 0;
    if (tid == 0) s_bl = 0;
    __syncthreads();
    const float4* row = lg4 + (size_t)b * NROW4;
    const int stride = 256 * gridDim.x;
    for (int i = blockIdx.x * 256 + tid; i < NROW4; i += stride) {
        float4 v = row[i];
        atomicAdd(&h[fkey(v.x) >> 19], 1u);
        atomicAdd(&h[fkey(v.y) >> 19], 1u);
        atomicAdd(&h[fkey(v.z) >> 19], 1u);
        atomicAdd(&h[fkey(v.w) >> 19], 1u);
    }
    __syncthreads();
    const int base = tid * 32;
    uint32_t s = 0;
#pragma unroll
    for (int k = 0; k < 32; ++k) s += h[base + k];
    csum[tid] = s;
    __syncthreads();
    for (int off = 1; off < 256; off <<= 1) {
        uint32_t v = csum[tid];
        uint32_t a = (tid + off < 256) ? csum[tid + off] : 0u;
        __syncthreads();
        csum[tid] = v + a;
        __syncthreads();
    }
    if (csum[tid] >= KSEL && (tid == 255 || csum[tid + 1] < KSEL)) {
        uint32_t ssum = (tid == 255) ? 0u : csum[tid + 1];
        int bl = base;
        for (int k = 31; k >= 0; --k) {
            ssum += h[base + k];
            if (ssum >= KSEL) { bl = base + k; break; }
        }
        s_bl = bl;
    }
    __syncthreads();
    const int bl = s_bl;
    uint32_t* gh = hist + (size_t)b * NBINS;
    for (int i = bl + tid; i < NBINS; i += 256) {
        uint32_t c = h[i];
        if (c) atomicAdd(&gh[i], c);
    }
}

// ---------------- fallback pass 2: threshold bin t* ----------------
__global__ void __launch_bounds__(1024) k_findbin(const uint32_t* __restrict__ hist,
                                                  const uint32_t* __restrict__ cnt,
                                                  uint32_t* __restrict__ tstar) {
    const int b = blockIdx.x;
    if (row_valid(cnt[b])) return;
    __shared__ uint32_t part[1024];
    const uint32_t* gh = hist + (size_t)b * NBINS;
    const int tid = threadIdx.x;
    const int base = tid * 8;
    uint32_t s = 0;
#pragma unroll
    for (int k = 0; k < 8; ++k) s += gh[base + k];
    part[tid] = s;
    __syncthreads();
    for (int off = 1; off < 1024; off <<= 1) {
        uint32_t v = part[tid];
        uint32_t add = (tid + off < 1024) ? part[tid + off] : 0u;
        __syncthreads();
        part[tid] = v + add;
        __syncthreads();
    }
    if (part[tid] >= KSEL && (tid == 1023 || part[tid + 1] < KSEL)) {
        uint32_t ssum = (tid == 1023) ? 0u : part[tid + 1];
        uint32_t t = (uint32_t)base;
        for (int k = 7; k >= 0; --k) {
            ssum += gh[base + k];
            if (ssum >= KSEL) { t = (uint32_t)(base + k); break; }
        }
        tstar[b] = t;
    }
}

// ---------------- fallback pass 3: collect ≥ t* (early-exit) ----------------
__global__ void __launch_bounds__(256) k_collect(const float4* __restrict__ lg4,
                                                 const uint32_t* __restrict__ tstar,
                                                 const uint32_t* __restrict__ cnt,
                                                 uint32_t* __restrict__ cnt_fb,
                                                 uint64_t* __restrict__ cand) {
    const int b = blockIdx.y;
    if (row_valid(cnt[b])) return;
    __shared__ uint64_t lbuf[LCAP];
    __shared__ uint32_t lcnt, lbase;
    const uint32_t ts = tstar[b];
    const int tid = threadIdx.x;
    if (tid == 0) lcnt = 0;
    __syncthreads();
    const float4* row = lg4 + (size_t)b * NROW4;
    uint32_t* pc = cnt_fb + b;
    uint64_t* pcand = cand + (size_t)b * CAPN;
    const int stride = 256 * gridDim.x;
    for (int i = blockIdx.x * 256 + tid; i < NROW4; i += stride) {
        float4 v = row[i];
        float c4[4] = {v.x, v.y, v.z, v.w};
#pragma unroll
        for (int j = 0; j < 4; ++j) {
            uint32_t u = fkey(c4[j]);
            if ((u >> 19) >= ts) {
                uint64_t pk = ((uint64_t)u << 32) | (uint32_t)(~(uint32_t)(i * 4 + j));
                uint32_t pos = atomicAdd(&lcnt, 1u);
                if (pos < LCAP) lbuf[pos] = pk;
                else { uint32_t g = atomicAdd(pc, 1u); if (g < CAPN) pcand[g] = pk; }
            }
        }
    }
    __syncthreads();
    uint32_t n = lcnt; if (n > LCAP) n = LCAP;
    if (tid == 0) lbase = atomicAdd(pc, n);
    __syncthreads();
    const uint32_t basep = lbase;
    for (uint32_t i2 = tid; i2 < n; i2 += 256) {
        uint32_t g = basep + i2;
        if (g < CAPN) pcand[g] = lbuf[i2];
    }
}

// ---------------- sort + main outputs ----------------
__global__ void __launch_bounds__(1024) k_sortout(const uint32_t* __restrict__ cnt,
                                                  const uint32_t* __restrict__ cnt_fb,
                                                  const uint64_t* __restrict__ cand,
                                                  const float4* __restrict__ pb4,
                                                  const float* __restrict__ tsz,
                                                  float* __restrict__ out,
                                                  int* __restrict__ qsel) {
    __shared__ uint64_t s[CAPN];
    const int b = blockIdx.x;
    const int tid = threadIdx.x;
    uint32_t c0 = cnt[b];
    uint32_t n = row_valid(c0) ? c0 : cnt_fb[b];
    if (n > CAPN) n = CAPN;
    const unsigned cap = (n <= 2048u) ? 2048u : 4096u;
    const uint64_t* pcand = cand + (size_t)b * CAPN;
    for (unsigned i = tid; i < cap; i += 1024) s[i] = (i < n) ? pcand[i] : 0ull;
    __syncthreads();
    // bitonic sort, descending by composite (key desc, idx asc on ties)
    for (unsigned k = 2; k <= cap; k <<= 1) {
        for (unsigned j = k >> 1; j > 0; j >>= 1) {
            for (unsigned base = 0; base < cap; base += 1024) {
                unsigned i = base + tid;
                unsigned ixj = i ^ j;
                if (ixj > i) {
                    uint64_t a = s[i], c = s[ixj];
                    bool up = ((i & k) == 0);
                    if (up ? (a < c) : (a > c)) { s[i] = c; s[ixj] = a; }
                }
            }
            __syncthreads();
        }
    }
    for (int jj = tid; jj < KSEL; jj += 1024) {
        uint64_t c = s[jj];
        uint32_t idx = ~((uint32_t)c);
        uint32_t q = idx / (uint32_t)CC;
        out[O_TIA + b * KSEL + jj] = (float)q;
    }
    if (tid < TOPKN) {
        uint64_t c = s[tid];
        uint32_t u = (uint32_t)(c >> 32);
        uint32_t idx = ~((uint32_t)c);
        uint32_t q = idx / (uint32_t)CC;
        uint32_t lab = idx - q * (uint32_t)CC;
        float logit = finv(u);
        out[O_SCORES + b * TOPKN + tid] = sigmoidf_(logit);
        out[O_LABELS + b * TOPKN + tid] = (float)lab;
        qsel[b * TOPKN + tid] = (int)q;
        float4 pb = pb4[b * QQ + q];
        float x0 = pb.x - 0.5f * pb.z;
        float y0 = pb.y - 0.5f * pb.w;
        float x1 = pb.x + 0.5f * pb.z;
        float y1 = pb.y + 0.5f * pb.w;
        float ih = tsz[b * 2 + 0];
        float iw = tsz[b * 2 + 1];
        float4* obn = (float4*)(out + O_BNORM);
        float4* obx = (float4*)(out + O_BOXES);
        obn[b * TOPKN + tid] = make_float4(x0, y0, x1, y1);
        obx[b * TOPKN + tid] = make_float4(x0 * iw, y0 * ih, x1 * iw, y1 * ih);
    }
}

// ---------------- topk_inst_prob gather + sigmoid ----------------
__global__ void __launch_bounds__(256) k_prob(const float* __restrict__ lg,
                                              const int* __restrict__ qsel,
                                              float* __restrict__ out) {
    const int r = blockIdx.x;          // 0..B*TOPK
    const int b = r / TOPKN;
    const int q = qsel[r];
    const float* src = lg + ((size_t)b * QQ + q) * CC;
    float* dst = out + O_PROB + (size_t)r * CC;
    for (int c = threadIdx.x; c < CC; c += 256) dst[c] = sigmoidf_(src[c]);
}

extern "C" void kernel_launch(void* const* d_in, const int* in_sizes, int n_in,
                              void* d_out, int out_size, void* d_ws, size_t ws_size,
                              hipStream_t stream) {
    const float* logits = (const float*)d_in[0];
    const float* boxes  = (const float*)d_in[1];
    const float* tsz    = (const float*)d_in[2];
    float* out = (float*)d_out;
    uint8_t* ws = (uint8_t*)d_ws;

    uint32_t* hist   = (uint32_t*)(ws + WS_HIST);
    uint32_t* tstar  = (uint32_t*)(ws + WS_TSTAR);
    uint32_t* cnt    = (uint32_t*)(ws + WS_CNT);
    uint32_t* cnt_fb = (uint32_t*)(ws + WS_CNTFB);
    uint64_t* cand   = (uint64_t*)(ws + WS_CAND);
    int*      qsel   = (int*)(ws + WS_QSEL);

    hipMemsetAsync(d_ws, 0, WS_ZERO_BYTES, stream);

    dim3 gs(GRIDX, BB);
    dim3 gf(FBX, BB);
    k_stash<<<gs, 256, 0, stream>>>((const float4*)logits, cnt, cand);
    k_hist<<<gf, 256, 0, stream>>>((const float4*)logits, cnt, hist);
    k_findbin<<<BB, 1024, 0, stream>>>(hist, cnt, tstar);
    k_collect<<<gf, 256, 0, stream>>>((const float4*)logits, tstar, cnt, cnt_fb, cand);
    k_sortout<<<BB, 1024, 0, stream>>>(cnt, cnt_fb, cand, (const float4*)boxes, tsz, out, qsel);
    k_prob<<<BB * TOPKN, 256, 0, stream>>>(logits, qsel, out);
}

// Round 4
// 110.984 us; speedup vs baseline: 4.6554x; 1.1387x over previous
//
#include <hip/hip_runtime.h>
#include <stdint.h>

#define BB   64
#define QQ   1000
#define CC   1203
#define NROW (QQ*CC)         // 1203000
#define NROW4 (NROW/4)       // 300750
#define KSEL 1000
#define TOPKN 100
#define NBINS 8192
#define CAPN 4096
#define SBUF 512
#define GRIDX 32
#define SPEC_VAL 3.0f        // speculative logit threshold: E[count]=1624/row, ~15 sigma above 1000, far below 4096

// workspace byte offsets
#define WS_CNT   0                               // 256 B, zeroed each call
#define WS_CAND  256
#define WS_QSEL  (WS_CAND + (size_t)BB*CAPN*8)
#define WS_ZERO_BYTES 256

// output float offsets (return-order concat)
#define O_SCORES 0
#define O_LABELS (BB*TOPKN)                      // 6400
#define O_BOXES  (2*BB*TOPKN)                    // 12800
#define O_PROB   (O_BOXES + BB*TOPKN*4)          // 38400
#define O_TIA    (O_PROB + (size_t)BB*TOPKN*CC)  // 7737600
#define O_BNORM  (O_TIA + BB*KSEL)               // 7801600

__device__ __forceinline__ uint32_t fkey(float f) {
    uint32_t x = __float_as_uint(f);
    return x ^ ((x & 0x80000000u) ? 0xFFFFFFFFu : 0x80000000u);
}
__device__ __forceinline__ float finv(uint32_t u) {
    uint32_t x = (u & 0x80000000u) ? (u ^ 0x80000000u) : ~u;
    return __uint_as_float(x);
}
__device__ __forceinline__ float sigmoidf_(float x) {
    if (x >= 0.0f) { float e = expf(-x); return 1.0f / (1.0f + e); }
    float e = expf(x); return e / (1.0f + e);
}
__device__ __forceinline__ bool row_valid(uint32_t c) {
    return c >= (uint32_t)KSEL && c <= (uint32_t)CAPN;
}

// ---------------- pass 1: single-pass speculative stash ----------------
__global__ void __launch_bounds__(256) k_stash(const float4* __restrict__ lg4,
                                               uint32_t* __restrict__ cnt,
                                               uint64_t* __restrict__ cand) {
    __shared__ uint64_t lbuf[SBUF];
    __shared__ uint32_t lcnt, lbase;
    const int b = blockIdx.y;
    const int tid = threadIdx.x;
    if (tid == 0) lcnt = 0;
    __syncthreads();
    const float4* row = lg4 + (size_t)b * NROW4;
    uint32_t* pc = cnt + b;
    uint64_t* pcand = cand + (size_t)b * CAPN;
    const int stride = 256 * GRIDX;

    int i = blockIdx.x * 256 + tid;
    for (; i + stride < NROW4; i += 2 * stride) {
        float4 v0 = row[i];
        float4 v1 = row[i + stride];
        float a0[4] = {v0.x, v0.y, v0.z, v0.w};
        float a1[4] = {v1.x, v1.y, v1.z, v1.w};
#pragma unroll
        for (int j = 0; j < 4; ++j) {
            if (a0[j] >= SPEC_VAL) {
                uint64_t pk = ((uint64_t)fkey(a0[j]) << 32) | (uint32_t)(~(uint32_t)(i * 4 + j));
                uint32_t pos = atomicAdd(&lcnt, 1u);
                if (pos < SBUF) lbuf[pos] = pk;
                else { uint32_t g = atomicAdd(pc, 1u); if (g < CAPN) pcand[g] = pk; }
            }
        }
#pragma unroll
        for (int j = 0; j < 4; ++j) {
            if (a1[j] >= SPEC_VAL) {
                uint64_t pk = ((uint64_t)fkey(a1[j]) << 32) | (uint32_t)(~(uint32_t)((i + stride) * 4 + j));
                uint32_t pos = atomicAdd(&lcnt, 1u);
                if (pos < SBUF) lbuf[pos] = pk;
                else { uint32_t g = atomicAdd(pc, 1u); if (g < CAPN) pcand[g] = pk; }
            }
        }
    }
    if (i < NROW4) {
        float4 v0 = row[i];
        float a0[4] = {v0.x, v0.y, v0.z, v0.w};
#pragma unroll
        for (int j = 0; j < 4; ++j) {
            if (a0[j] >= SPEC_VAL) {
                uint64_t pk = ((uint64_t)fkey(a0[j]) << 32) | (uint32_t)(~(uint32_t)(i * 4 + j));
                uint32_t pos = atomicAdd(&lcnt, 1u);
                if (pos < SBUF) lbuf[pos] = pk;
                else { uint32_t g = atomicAdd(pc, 1u); if (g < CAPN) pcand[g] = pk; }
            }
        }
    }
    __syncthreads();
    uint32_t n = lcnt; if (n > SBUF) n = SBUF;
    if (tid == 0) lbase = atomicAdd(pc, n);
    __syncthreads();
    const uint32_t basep = lbase;
    for (uint32_t i2 = tid; i2 < n; i2 += 256) {
        uint32_t g = basep + i2;
        if (g < CAPN) pcand[g] = lbuf[i2];
    }
}

// ---------------- pass 2: sort + outputs; in-block fallback if stash invalid ----------------
__global__ void __launch_bounds__(1024) k_sortout(const float4* __restrict__ lg4,
                                                  const uint32_t* __restrict__ cnt,
                                                  const uint64_t* __restrict__ cand,
                                                  const float4* __restrict__ pb4,
                                                  const float* __restrict__ tsz,
                                                  float* __restrict__ out,
                                                  int* __restrict__ qsel) {
    __shared__ uint64_t s[CAPN];          // 32 KiB; aliased as uint32 hist in fallback
    __shared__ uint32_t csum[1024];
    __shared__ uint32_t sh_n;
    __shared__ int sh_t;
    const int b = blockIdx.x;
    const int tid = threadIdx.x;
    const uint64_t* pcand = cand + (size_t)b * CAPN;
    uint32_t c0 = cnt[b];
    uint32_t n;

    if (row_valid(c0)) {
        n = c0;
        for (uint32_t i = tid; i < n; i += 1024) s[i] = pcand[i];
    } else {
        // ---- fallback: exact per-row selection, fully in-block (never taken for sane data) ----
        uint32_t* hs = (uint32_t*)s;
        for (int i = tid; i < NBINS; i += 1024) hs[i] = 0;
        __syncthreads();
        const float4* row = lg4 + (size_t)b * NROW4;
        for (int i = tid; i < NROW4; i += 1024) {
            float4 v = row[i];
            atomicAdd(&hs[fkey(v.x) >> 19], 1u);
            atomicAdd(&hs[fkey(v.y) >> 19], 1u);
            atomicAdd(&hs[fkey(v.z) >> 19], 1u);
            atomicAdd(&hs[fkey(v.w) >> 19], 1u);
        }
        __syncthreads();
        const int base = tid * 8;
        uint32_t ssum = 0;
#pragma unroll
        for (int k = 0; k < 8; ++k) ssum += hs[base + k];
        csum[tid] = ssum;
        __syncthreads();
        for (int off = 1; off < 1024; off <<= 1) {
            uint32_t v = csum[tid];
            uint32_t a = (tid + off < 1024) ? csum[tid + off] : 0u;
            __syncthreads();
            csum[tid] = v + a;
            __syncthreads();
        }
        if (csum[tid] >= KSEL && (tid == 1023 || csum[tid + 1] < KSEL)) {
            uint32_t acc = (tid == 1023) ? 0u : csum[tid + 1];
            int t = base;
            for (int k = 7; k >= 0; --k) {
                acc += hs[base + k];
                if (acc >= KSEL) { t = base + k; break; }
            }
            sh_t = t;
        }
        if (tid == 0) sh_n = 0;
        __syncthreads();
        const uint32_t ts = (uint32_t)sh_t;   // after this barrier nobody reads hs again
        for (int i = tid; i < NROW4; i += 1024) {
            float4 v = row[i];
            float c4[4] = {v.x, v.y, v.z, v.w};
#pragma unroll
            for (int j = 0; j < 4; ++j) {
                uint32_t u = fkey(c4[j]);
                if ((u >> 19) >= ts) {
                    uint32_t pos = atomicAdd(&sh_n, 1u);
                    if (pos < CAPN)
                        s[pos] = ((uint64_t)u << 32) | (uint32_t)(~(uint32_t)(i * 4 + j));
                }
            }
        }
        __syncthreads();
        n = sh_n;
    }
    if (n > CAPN) n = CAPN;
    const unsigned cap = (n <= 2048u) ? 2048u : 4096u;
    for (unsigned i = n + tid; i < cap; i += 1024) s[i] = 0ull;
    __syncthreads();

    // bitonic sort, descending by composite (key desc, idx asc on ties)
    for (unsigned k = 2; k <= cap; k <<= 1) {
        for (unsigned j = k >> 1; j > 0; j >>= 1) {
            for (unsigned base2 = 0; base2 < cap; base2 += 1024) {
                unsigned i = base2 + tid;
                unsigned ixj = i ^ j;
                if (ixj > i) {
                    uint64_t a = s[i], c = s[ixj];
                    bool up = ((i & k) == 0);
                    if (up ? (a < c) : (a > c)) { s[i] = c; s[ixj] = a; }
                }
            }
            __syncthreads();
        }
    }

    for (int jj = tid; jj < KSEL; jj += 1024) {
        uint64_t c = s[jj];
        uint32_t idx = ~((uint32_t)c);
        uint32_t q = idx / (uint32_t)CC;
        out[O_TIA + b * KSEL + jj] = (float)q;
    }
    if (tid < TOPKN) {
        uint64_t c = s[tid];
        uint32_t u = (uint32_t)(c >> 32);
        uint32_t idx = ~((uint32_t)c);
        uint32_t q = idx / (uint32_t)CC;
        uint32_t lab = idx - q * (uint32_t)CC;
        float logit = finv(u);
        out[O_SCORES + b * TOPKN + tid] = sigmoidf_(logit);
        out[O_LABELS + b * TOPKN + tid] = (float)lab;
        qsel[b * TOPKN + tid] = (int)q;
        float4 pb = pb4[b * QQ + q];
        float x0 = pb.x - 0.5f * pb.z;
        float y0 = pb.y - 0.5f * pb.w;
        float x1 = pb.x + 0.5f * pb.z;
        float y1 = pb.y + 0.5f * pb.w;
        float ih = tsz[b * 2 + 0];
        float iw = tsz[b * 2 + 1];
        float4* obn = (float4*)(out + O_BNORM);
        float4* obx = (float4*)(out + O_BOXES);
        obn[b * TOPKN + tid] = make_float4(x0, y0, x1, y1);
        obx[b * TOPKN + tid] = make_float4(x0 * iw, y0 * ih, x1 * iw, y1 * ih);
    }
}

// ---------------- pass 3: topk_inst_prob gather + sigmoid ----------------
__global__ void __launch_bounds__(256) k_prob(const float* __restrict__ lg,
                                              const int* __restrict__ qsel,
                                              float* __restrict__ out) {
    const int r = blockIdx.x;          // 0..B*TOPK
    const int b = r / TOPKN;
    const int q = qsel[r];
    const float* src = lg + ((size_t)b * QQ + q) * CC;
    float* dst = out + O_PROB + (size_t)r * CC;
    for (int c = threadIdx.x; c < CC; c += 256) dst[c] = sigmoidf_(src[c]);
}

extern "C" void kernel_launch(void* const* d_in, const int* in_sizes, int n_in,
                              void* d_out, int out_size, void* d_ws, size_t ws_size,
                              hipStream_t stream) {
    const float* logits = (const float*)d_in[0];
    const float* boxes  = (const float*)d_in[1];
    const float* tsz    = (const float*)d_in[2];
    float* out = (float*)d_out;
    uint8_t* ws = (uint8_t*)d_ws;

    uint32_t* cnt  = (uint32_t*)(ws + WS_CNT);
    uint64_t* cand = (uint64_t*)(ws + WS_CAND);
    int*      qsel = (int*)(ws + WS_QSEL);

    hipMemsetAsync(cnt, 0, WS_ZERO_BYTES, stream);

    dim3 gs(GRIDX, BB);
    k_stash<<<gs, 256, 0, stream>>>((const float4*)logits, cnt, cand);
    k_sortout<<<BB, 1024, 0, stream>>>((const float4*)logits, cnt, cand,
                                       (const float4*)boxes, tsz, out, qsel);
    k_prob<<<BB * TOPKN, 256, 0, stream>>>(logits, qsel, out);
}

// Round 5
// 105.743 us; speedup vs baseline: 4.8861x; 1.0496x over previous
//
#include <hip/hip_runtime.h>
#include <stdint.h>

#define BB   64
#define QQ   1000
#define CC   1203
#define NROW (QQ*CC)         // 1203000
#define NROW4 (NROW/4)       // 300750
#define KSEL 1000
#define TOPKN 100
#define NBINS 8192
#define CAPN 4096
#define SLICE 128            // cand slots per (row, block); 32 blocks * 128 = 4096 = CAPN
#define GRIDX 32
#define SPEC_VAL 3.0f        // speculative threshold: row mean 1624 (15 sigma > 1000), block mean 51 (11 sigma < 128)

// workspace byte offsets (no zeroing needed: every word read is overwritten first)
#define WS_BCNT  0                                   // BB*GRIDX*4 = 8192 B
#define WS_CAND  (BB*GRIDX*4)
#define WS_QSEL  (WS_CAND + (size_t)BB*CAPN*8)

// output float offsets (return-order concat)
#define O_SCORES 0
#define O_LABELS (BB*TOPKN)                      // 6400
#define O_BOXES  (2*BB*TOPKN)                    // 12800
#define O_PROB   (O_BOXES + BB*TOPKN*4)          // 38400
#define O_TIA    (O_PROB + (size_t)BB*TOPKN*CC)  // 7737600
#define O_BNORM  (O_TIA + BB*KSEL)               // 7801600

__device__ __forceinline__ uint32_t fkey(float f) {
    uint32_t x = __float_as_uint(f);
    return x ^ ((x & 0x80000000u) ? 0xFFFFFFFFu : 0x80000000u);
}
__device__ __forceinline__ float finv(uint32_t u) {
    uint32_t x = (u & 0x80000000u) ? (u ^ 0x80000000u) : ~u;
    return __uint_as_float(x);
}
__device__ __forceinline__ float sigmoidf_(float x) {
    if (x >= 0.0f) { float e = expf(-x); return 1.0f / (1.0f + e); }
    float e = expf(x); return e / (1.0f + e);
}

// ---------------- pass 1: single-pass speculative stash (no global atomics) ----------------
__device__ __forceinline__ void stash_elem(float val, uint32_t idx,
                                           uint32_t* lcnt, uint64_t* lbuf) {
    uint64_t pk = ((uint64_t)fkey(val) << 32) | (uint32_t)(~idx);
    uint32_t pos = atomicAdd(lcnt, 1u);
    if (pos < SLICE) lbuf[pos] = pk;
}
__device__ __forceinline__ void stash_vec(float4 v, int i4,
                                          uint32_t* lcnt, uint64_t* lbuf) {
    float m = fmaxf(fmaxf(v.x, v.y), fmaxf(v.z, v.w));
    if (m >= SPEC_VAL) {                       // one branch per 4 elems; body is rare
        if (v.x >= SPEC_VAL) stash_elem(v.x, (uint32_t)(i4 * 4 + 0), lcnt, lbuf);
        if (v.y >= SPEC_VAL) stash_elem(v.y, (uint32_t)(i4 * 4 + 1), lcnt, lbuf);
        if (v.z >= SPEC_VAL) stash_elem(v.z, (uint32_t)(i4 * 4 + 2), lcnt, lbuf);
        if (v.w >= SPEC_VAL) stash_elem(v.w, (uint32_t)(i4 * 4 + 3), lcnt, lbuf);
    }
}

__global__ void __launch_bounds__(256) k_stash(const float4* __restrict__ lg4,
                                               uint32_t* __restrict__ bcnt,
                                               uint64_t* __restrict__ cand) {
    __shared__ uint64_t lbuf[SLICE];
    __shared__ uint32_t lcnt;
    const int b = blockIdx.y;
    const int blk = blockIdx.x;
    const int tid = threadIdx.x;
    if (tid == 0) lcnt = 0;
    __syncthreads();
    const float4* row = lg4 + (size_t)b * NROW4;
    const int stride = 256 * GRIDX;

    int i = blk * 256 + tid;
    for (; i + 3 * stride < NROW4; i += 4 * stride) {
        float4 v0 = row[i];
        float4 v1 = row[i + stride];
        float4 v2 = row[i + 2 * stride];
        float4 v3 = row[i + 3 * stride];
        stash_vec(v0, i,              &lcnt, lbuf);
        stash_vec(v1, i + stride,     &lcnt, lbuf);
        stash_vec(v2, i + 2 * stride, &lcnt, lbuf);
        stash_vec(v3, i + 3 * stride, &lcnt, lbuf);
    }
    for (; i < NROW4; i += stride) {
        float4 v = row[i];
        stash_vec(v, i, &lcnt, lbuf);
    }
    __syncthreads();
    const uint32_t c = lcnt;
    uint64_t* slice = cand + ((size_t)b * GRIDX + blk) * SLICE;
    uint32_t n = (c < SLICE) ? c : SLICE;
    for (uint32_t i2 = tid; i2 < n; i2 += 256) slice[i2] = lbuf[i2];
    if (tid == 0) bcnt[b * GRIDX + blk] = c;   // overwrite (deterministic, no init needed)
}

// ---------------- pass 2: compact + sort + outputs; in-block exact fallback ----------------
__global__ void __launch_bounds__(1024) k_sortout(const float4* __restrict__ lg4,
                                                  const uint32_t* __restrict__ bcnt,
                                                  const uint64_t* __restrict__ cand,
                                                  const float4* __restrict__ pb4,
                                                  const float* __restrict__ tsz,
                                                  float* __restrict__ out,
                                                  int* __restrict__ qsel) {
    __shared__ uint64_t s[CAPN];          // 32 KiB; aliased as uint32 hist in fallback
    __shared__ uint32_t csum[1024];
    __shared__ uint32_t scnt[GRIDX], soff[GRIDX + 1];
    __shared__ int sh_valid;
    __shared__ uint32_t sh_n;
    __shared__ int sh_t;
    const int b = blockIdx.x;
    const int tid = threadIdx.x;
    const uint64_t* pcand = cand + (size_t)b * CAPN;
    uint32_t n;

    if (tid == 0) {
        uint32_t acc = 0;
        int ok = 1;
        for (int k = 0; k < GRIDX; ++k) {
            uint32_t c = bcnt[b * GRIDX + k];
            if (c > SLICE) ok = 0;
            scnt[k] = (c < SLICE) ? c : SLICE;
            soff[k] = acc;
            acc += scnt[k];
        }
        soff[GRIDX] = acc;
        sh_valid = ok && acc >= (uint32_t)KSEL;
    }
    __syncthreads();

    if (sh_valid) {
        n = soff[GRIDX];
        // 8 slices per pass, 4 passes (tid>>7 in 0..7, idx = tid&127)
#pragma unroll
        for (int p = 0; p < 4; ++p) {
            int k = p * 8 + (tid >> 7);
            int idx = tid & 127;
            if ((uint32_t)idx < scnt[k]) s[soff[k] + idx] = pcand[k * SLICE + idx];
        }
    } else {
        // ---- fallback: exact per-row selection, fully in-block (never taken for sane data) ----
        uint32_t* hs = (uint32_t*)s;
        for (int i = tid; i < NBINS; i += 1024) hs[i] = 0;
        __syncthreads();
        const float4* row = lg4 + (size_t)b * NROW4;
        for (int i = tid; i < NROW4; i += 1024) {
            float4 v = row[i];
            atomicAdd(&hs[fkey(v.x) >> 19], 1u);
            atomicAdd(&hs[fkey(v.y) >> 19], 1u);
            atomicAdd(&hs[fkey(v.z) >> 19], 1u);
            atomicAdd(&hs[fkey(v.w) >> 19], 1u);
        }
        __syncthreads();
        const int base = tid * 8;
        uint32_t ssum = 0;
#pragma unroll
        for (int k = 0; k < 8; ++k) ssum += hs[base + k];
        csum[tid] = ssum;
        __syncthreads();
        for (int off = 1; off < 1024; off <<= 1) {
            uint32_t v = csum[tid];
            uint32_t a = (tid + off < 1024) ? csum[tid + off] : 0u;
            __syncthreads();
            csum[tid] = v + a;
            __syncthreads();
        }
        if (csum[tid] >= KSEL && (tid == 1023 || csum[tid + 1] < KSEL)) {
            uint32_t acc = (tid == 1023) ? 0u : csum[tid + 1];
            int t = base;
            for (int k = 7; k >= 0; --k) {
                acc += hs[base + k];
                if (acc >= KSEL) { t = base + k; break; }
            }
            sh_t = t;
        }
        if (tid == 0) sh_n = 0;
        __syncthreads();
        const uint32_t ts = (uint32_t)sh_t;   // after this barrier nobody reads hs again
        for (int i = tid; i < NROW4; i += 1024) {
            float4 v = row[i];
            float c4[4] = {v.x, v.y, v.z, v.w};
#pragma unroll
            for (int j = 0; j < 4; ++j) {
                uint32_t u = fkey(c4[j]);
                if ((u >> 19) >= ts) {
                    uint32_t pos = atomicAdd(&sh_n, 1u);
                    if (pos < CAPN)
                        s[pos] = ((uint64_t)u << 32) | (uint32_t)(~(uint32_t)(i * 4 + j));
                }
            }
        }
        __syncthreads();
        n = sh_n;
    }
    if (n > CAPN) n = CAPN;
    const unsigned cap = (n <= 2048u) ? 2048u : 4096u;
    for (unsigned i = n + tid; i < cap; i += 1024) s[i] = 0ull;
    __syncthreads();

    // bitonic sort, descending by composite (key desc, idx asc on ties)
    for (unsigned k = 2; k <= cap; k <<= 1) {
        for (unsigned j = k >> 1; j > 0; j >>= 1) {
            for (unsigned base2 = 0; base2 < cap; base2 += 1024) {
                unsigned i = base2 + tid;
                unsigned ixj = i ^ j;
                if (ixj > i) {
                    uint64_t a = s[i], c = s[ixj];
                    bool up = ((i & k) == 0);
                    if (up ? (a < c) : (a > c)) { s[i] = c; s[ixj] = a; }
                }
            }
            __syncthreads();
        }
    }

    for (int jj = tid; jj < KSEL; jj += 1024) {
        uint64_t c = s[jj];
        uint32_t idx = ~((uint32_t)c);
        uint32_t q = idx / (uint32_t)CC;
        out[O_TIA + b * KSEL + jj] = (float)q;
    }
    if (tid < TOPKN) {
        uint64_t c = s[tid];
        uint32_t u = (uint32_t)(c >> 32);
        uint32_t idx = ~((uint32_t)c);
        uint32_t q = idx / (uint32_t)CC;
        uint32_t lab = idx - q * (uint32_t)CC;
        float logit = finv(u);
        out[O_SCORES + b * TOPKN + tid] = sigmoidf_(logit);
        out[O_LABELS + b * TOPKN + tid] = (float)lab;
        qsel[b * TOPKN + tid] = (int)q;
        float4 pb = pb4[b * QQ + q];
        float x0 = pb.x - 0.5f * pb.z;
        float y0 = pb.y - 0.5f * pb.w;
        float x1 = pb.x + 0.5f * pb.z;
        float y1 = pb.y + 0.5f * pb.w;
        float ih = tsz[b * 2 + 0];
        float iw = tsz[b * 2 + 1];
        float4* obn = (float4*)(out + O_BNORM);
        float4* obx = (float4*)(out + O_BOXES);
        obn[b * TOPKN + tid] = make_float4(x0, y0, x1, y1);
        obx[b * TOPKN + tid] = make_float4(x0 * iw, y0 * ih, x1 * iw, y1 * ih);
    }
}

// ---------------- pass 3: topk_inst_prob gather + sigmoid ----------------
__global__ void __launch_bounds__(256) k_prob(const float* __restrict__ lg,
                                              const int* __restrict__ qsel,
                                              float* __restrict__ out) {
    const int r = blockIdx.x;          // 0..B*TOPK
    const int b = r / TOPKN;
    const int q = qsel[r];
    const float* src = lg + ((size_t)b * QQ + q) * CC;
    float* dst = out + O_PROB + (size_t)r * CC;
    for (int c = threadIdx.x; c < CC; c += 256) dst[c] = sigmoidf_(src[c]);
}

extern "C" void kernel_launch(void* const* d_in, const int* in_sizes, int n_in,
                              void* d_out, int out_size, void* d_ws, size_t ws_size,
                              hipStream_t stream) {
    const float* logits = (const float*)d_in[0];
    const float* boxes  = (const float*)d_in[1];
    const float* tsz    = (const float*)d_in[2];
    float* out = (float*)d_out;
    uint8_t* ws = (uint8_t*)d_ws;

    uint32_t* bcnt = (uint32_t*)(ws + WS_BCNT);
    uint64_t* cand = (uint64_t*)(ws + WS_CAND);
    int*      qsel = (int*)(ws + WS_QSEL);

    dim3 gs(GRIDX, BB);
    k_stash<<<gs, 256, 0, stream>>>((const float4*)logits, bcnt, cand);
    k_sortout<<<BB, 1024, 0, stream>>>((const float4*)logits, bcnt, cand,
                                       (const float4*)boxes, tsz, out, qsel);
    k_prob<<<BB * TOPKN, 256, 0, stream>>>(logits, qsel, out);
}

// Round 6
// 96.386 us; speedup vs baseline: 5.3605x; 1.0971x over previous
//
#include <hip/hip_runtime.h>
#include <stdint.h>

#define BB   64
#define QQ   1000
#define CC   1203
#define NROW (QQ*CC)         // 1203000
#define NROW4 (NROW/4)       // 300750
#define KSEL 1000
#define TOPKN 100
#define NBINS 8192
#define CAPN 4096
#define SLICE 128            // cand slots per (row, chunk); 32 * 128 = 4096 = CAPN
#define GRIDX 32
#define CHUNK ((NROW4 + GRIDX - 1) / GRIDX)   // 9399 float4 per block, contiguous
#define SPEC_VAL 3.0f        // row mean 1624 (15 sigma > 1000); chunk mean 51 (11 sigma < 128)

// workspace byte offsets (no zeroing needed: every word read is overwritten first)
#define WS_BCNT  0                                   // BB*GRIDX*4 = 8192 B
#define WS_CAND  (BB*GRIDX*4)
#define WS_QSEL  (WS_CAND + (size_t)BB*CAPN*8)

// output float offsets (return-order concat)
#define O_SCORES 0
#define O_LABELS (BB*TOPKN)                      // 6400
#define O_BOXES  (2*BB*TOPKN)                    // 12800
#define O_PROB   (O_BOXES + BB*TOPKN*4)          // 38400
#define O_TIA    (O_PROB + (size_t)BB*TOPKN*CC)  // 7737600
#define O_BNORM  (O_TIA + BB*KSEL)               // 7801600

__device__ __forceinline__ uint32_t fkey(float f) {
    uint32_t x = __float_as_uint(f);
    return x ^ ((x & 0x80000000u) ? 0xFFFFFFFFu : 0x80000000u);
}
__device__ __forceinline__ float finv(uint32_t u) {
    uint32_t x = (u & 0x80000000u) ? (u ^ 0x80000000u) : ~u;
    return __uint_as_float(x);
}
__device__ __forceinline__ float sigmoidf_(float x) {
    if (x >= 0.0f) { float e = expf(-x); return 1.0f / (1.0f + e); }
    float e = expf(x); return e / (1.0f + e);
}

// ---------------- pass 1: single-pass speculative stash, contiguous chunk/block --------
__device__ __forceinline__ void stash_elem(float val, uint32_t idx,
                                           uint32_t* lcnt, uint64_t* lbuf) {
    uint64_t pk = ((uint64_t)fkey(val) << 32) | (uint32_t)(~idx);
    uint32_t pos = atomicAdd(lcnt, 1u);
    if (pos < SLICE) lbuf[pos] = pk;
}
__device__ __forceinline__ void stash_vec(float4 v, int i4,
                                          uint32_t* lcnt, uint64_t* lbuf) {
    float m = fmaxf(fmaxf(v.x, v.y), fmaxf(v.z, v.w));
    if (m >= SPEC_VAL) {                       // one branch per 4 elems; body is rare
        if (v.x >= SPEC_VAL) stash_elem(v.x, (uint32_t)(i4 * 4 + 0), lcnt, lbuf);
        if (v.y >= SPEC_VAL) stash_elem(v.y, (uint32_t)(i4 * 4 + 1), lcnt, lbuf);
        if (v.z >= SPEC_VAL) stash_elem(v.z, (uint32_t)(i4 * 4 + 2), lcnt, lbuf);
        if (v.w >= SPEC_VAL) stash_elem(v.w, (uint32_t)(i4 * 4 + 3), lcnt, lbuf);
    }
}

__global__ void __launch_bounds__(256) k_stash(const float4* __restrict__ lg4,
                                               uint32_t* __restrict__ bcnt,
                                               uint64_t* __restrict__ cand) {
    __shared__ uint64_t lbuf[SLICE];
    __shared__ uint32_t lcnt;
    const int b = blockIdx.y;
    const int blk = blockIdx.x;
    const int tid = threadIdx.x;
    if (tid == 0) lcnt = 0;
    __syncthreads();
    const float4* row = lg4 + (size_t)b * NROW4;
    const int start = blk * CHUNK;
    const int end = (start + CHUNK < NROW4) ? (start + CHUNK) : NROW4;

    int i = start + tid;
    // block streams one contiguous chunk; each iteration covers 16 KB contiguous
    for (; i + 768 < end; i += 1024) {
        float4 v0 = row[i];
        float4 v1 = row[i + 256];
        float4 v2 = row[i + 512];
        float4 v3 = row[i + 768];
        stash_vec(v0, i,       &lcnt, lbuf);
        stash_vec(v1, i + 256, &lcnt, lbuf);
        stash_vec(v2, i + 512, &lcnt, lbuf);
        stash_vec(v3, i + 768, &lcnt, lbuf);
    }
    for (; i < end; i += 256) {
        float4 v = row[i];
        stash_vec(v, i, &lcnt, lbuf);
    }
    __syncthreads();
    const uint32_t c = lcnt;
    uint64_t* slice = cand + ((size_t)b * GRIDX + blk) * SLICE;
    uint32_t n = (c < SLICE) ? c : SLICE;
    for (uint32_t i2 = tid; i2 < n; i2 += 256) slice[i2] = lbuf[i2];
    if (tid == 0) bcnt[b * GRIDX + blk] = c;   // overwrite (deterministic, no init needed)
}

// ---------------- pass 2: compact + sort + outputs; in-block exact fallback ----------------
__global__ void __launch_bounds__(1024) k_sortout(const float4* __restrict__ lg4,
                                                  const uint32_t* __restrict__ bcnt,
                                                  const uint64_t* __restrict__ cand,
                                                  const float4* __restrict__ pb4,
                                                  const float* __restrict__ tsz,
                                                  float* __restrict__ out,
                                                  int* __restrict__ qsel) {
    __shared__ uint64_t s[CAPN];          // 32 KiB; aliased as uint32 hist in fallback
    __shared__ uint32_t csum[1024];
    __shared__ uint32_t scnt[GRIDX], soff[GRIDX + 1];
    __shared__ int sh_valid;
    __shared__ uint32_t sh_n;
    __shared__ int sh_t;
    const int b = blockIdx.x;
    const int tid = threadIdx.x;
    const uint64_t* pcand = cand + (size_t)b * CAPN;
    uint32_t n;

    if (tid == 0) {
        uint32_t acc = 0;
        int ok = 1;
        for (int k = 0; k < GRIDX; ++k) {
            uint32_t c = bcnt[b * GRIDX + k];
            if (c > SLICE) ok = 0;
            scnt[k] = (c < SLICE) ? c : SLICE;
            soff[k] = acc;
            acc += scnt[k];
        }
        soff[GRIDX] = acc;
        sh_valid = ok && acc >= (uint32_t)KSEL;
    }
    __syncthreads();

    if (sh_valid) {
        n = soff[GRIDX];
        // 8 slices per pass, 4 passes (tid>>7 in 0..7, idx = tid&127)
#pragma unroll
        for (int p = 0; p < 4; ++p) {
            int k = p * 8 + (tid >> 7);
            int idx = tid & 127;
            if ((uint32_t)idx < scnt[k]) s[soff[k] + idx] = pcand[k * SLICE + idx];
        }
    } else {
        // ---- fallback: exact per-row selection, fully in-block (never taken for sane data) ----
        uint32_t* hs = (uint32_t*)s;
        for (int i = tid; i < NBINS; i += 1024) hs[i] = 0;
        __syncthreads();
        const float4* row = lg4 + (size_t)b * NROW4;
        for (int i = tid; i < NROW4; i += 1024) {
            float4 v = row[i];
            atomicAdd(&hs[fkey(v.x) >> 19], 1u);
            atomicAdd(&hs[fkey(v.y) >> 19], 1u);
            atomicAdd(&hs[fkey(v.z) >> 19], 1u);
            atomicAdd(&hs[fkey(v.w) >> 19], 1u);
        }
        __syncthreads();
        const int base = tid * 8;
        uint32_t ssum = 0;
#pragma unroll
        for (int k = 0; k < 8; ++k) ssum += hs[base + k];
        csum[tid] = ssum;
        __syncthreads();
        for (int off = 1; off < 1024; off <<= 1) {
            uint32_t v = csum[tid];
            uint32_t a = (tid + off < 1024) ? csum[tid + off] : 0u;
            __syncthreads();
            csum[tid] = v + a;
            __syncthreads();
        }
        if (csum[tid] >= KSEL && (tid == 1023 || csum[tid + 1] < KSEL)) {
            uint32_t acc = (tid == 1023) ? 0u : csum[tid + 1];
            int t = base;
            for (int k = 7; k >= 0; --k) {
                acc += hs[base + k];
                if (acc >= KSEL) { t = base + k; break; }
            }
            sh_t = t;
        }
        if (tid == 0) sh_n = 0;
        __syncthreads();
        const uint32_t ts = (uint32_t)sh_t;   // after this barrier nobody reads hs again
        for (int i = tid; i < NROW4; i += 1024) {
            float4 v = row[i];
            float c4[4] = {v.x, v.y, v.z, v.w};
#pragma unroll
            for (int j = 0; j < 4; ++j) {
                uint32_t u = fkey(c4[j]);
                if ((u >> 19) >= ts) {
                    uint32_t pos = atomicAdd(&sh_n, 1u);
                    if (pos < CAPN)
                        s[pos] = ((uint64_t)u << 32) | (uint32_t)(~(uint32_t)(i * 4 + j));
                }
            }
        }
        __syncthreads();
        n = sh_n;
    }
    if (n > CAPN) n = CAPN;
    const unsigned cap = (n <= 2048u) ? 2048u : 4096u;
    for (unsigned i = n + tid; i < cap; i += 1024) s[i] = 0ull;
    __syncthreads();

    // bitonic sort, descending composite (key desc, idx asc on ties)
    // direct pair indexing: exactly cap/2 compare-exchanges per step, no idle pass
    for (unsigned k = 2; k <= cap; k <<= 1) {
        for (unsigned j = k >> 1; j > 0; j >>= 1) {
            for (unsigned w = tid; w < (cap >> 1); w += 1024) {
                unsigned i = ((w & ~(j - 1)) << 1) | (w & (j - 1));
                unsigned ixj = i | j;
                uint64_t a = s[i], c = s[ixj];
                bool up = ((i & k) == 0);
                if (up ? (a < c) : (a > c)) { s[i] = c; s[ixj] = a; }
            }
            __syncthreads();
        }
    }

    for (int jj = tid; jj < KSEL; jj += 1024) {
        uint64_t c = s[jj];
        uint32_t idx = ~((uint32_t)c);
        uint32_t q = idx / (uint32_t)CC;
        out[O_TIA + b * KSEL + jj] = (float)q;
    }
    if (tid < TOPKN) {
        uint64_t c = s[tid];
        uint32_t u = (uint32_t)(c >> 32);
        uint32_t idx = ~((uint32_t)c);
        uint32_t q = idx / (uint32_t)CC;
        uint32_t lab = idx - q * (uint32_t)CC;
        float logit = finv(u);
        out[O_SCORES + b * TOPKN + tid] = sigmoidf_(logit);
        out[O_LABELS + b * TOPKN + tid] = (float)lab;
        qsel[b * TOPKN + tid] = (int)q;
        float4 pb = pb4[b * QQ + q];
        float x0 = pb.x - 0.5f * pb.z;
        float y0 = pb.y - 0.5f * pb.w;
        float x1 = pb.x + 0.5f * pb.z;
        float y1 = pb.y + 0.5f * pb.w;
        float ih = tsz[b * 2 + 0];
        float iw = tsz[b * 2 + 1];
        float4* obn = (float4*)(out + O_BNORM);
        float4* obx = (float4*)(out + O_BOXES);
        obn[b * TOPKN + tid] = make_float4(x0, y0, x1, y1);
        obx[b * TOPKN + tid] = make_float4(x0 * iw, y0 * ih, x1 * iw, y1 * ih);
    }
}

// ---------------- pass 3: topk_inst_prob gather + sigmoid ----------------
__global__ void __launch_bounds__(256) k_prob(const float* __restrict__ lg,
                                              const int* __restrict__ qsel,
                                              float* __restrict__ out) {
    const int r = blockIdx.x;          // 0..B*TOPK
    const int b = r / TOPKN;
    const int q = qsel[r];
    const float* src = lg + ((size_t)b * QQ + q) * CC;
    float* dst = out + O_PROB + (size_t)r * CC;
    for (int c = threadIdx.x; c < CC; c += 256) dst[c] = sigmoidf_(src[c]);
}

extern "C" void kernel_launch(void* const* d_in, const int* in_sizes, int n_in,
                              void* d_out, int out_size, void* d_ws, size_t ws_size,
                              hipStream_t stream) {
    const float* logits = (const float*)d_in[0];
    const float* boxes  = (const float*)d_in[1];
    const float* tsz    = (const float*)d_in[2];
    float* out = (float*)d_out;
    uint8_t* ws = (uint8_t*)d_ws;

    uint32_t* bcnt = (uint32_t*)(ws + WS_BCNT);
    uint64_t* cand = (uint64_t*)(ws + WS_CAND);
    int*      qsel = (int*)(ws + WS_QSEL);

    dim3 gs(GRIDX, BB);
    k_stash<<<gs, 256, 0, stream>>>((const float4*)logits, bcnt, cand);
    k_sortout<<<BB, 1024, 0, stream>>>((const float4*)logits, bcnt, cand,
                                       (const float4*)boxes, tsz, out, qsel);
    k_prob<<<BB * TOPKN, 256, 0, stream>>>(logits, qsel, out);
}

// Round 7
// 93.534 us; speedup vs baseline: 5.5239x; 1.0305x over previous
//
#include <hip/hip_runtime.h>
#include <stdint.h>

#define BB   64
#define QQ   1000
#define CC   1203
#define NROW (QQ*CC)         // 1203000
#define NROW4 (NROW/4)       // 300750
#define KSEL 1000
#define TOPKN 100
#define NBINS 8192
#define CAPN 4096
#define SLICE 64             // cand slots per (row, chunk); 64 * 64 = 4096 = CAPN
#define GRIDX 64
#define CHUNK ((NROW4 + GRIDX - 1) / GRIDX)   // 4700 float4 per block, contiguous
#define SPEC_VAL 3.0f        // row mean 1624 (15 sigma > 1000); chunk mean 25.4 (7.9 sigma < 64)

// workspace byte offsets (no zeroing needed: every word read is overwritten first)
#define WS_BCNT  0                                   // BB*GRIDX*4 = 16384 B
#define WS_CAND  (BB*GRIDX*4)
#define WS_QSEL  (WS_CAND + (size_t)BB*CAPN*8)

// output float offsets (return-order concat)
#define O_SCORES 0
#define O_LABELS (BB*TOPKN)                      // 6400
#define O_BOXES  (2*BB*TOPKN)                    // 12800
#define O_PROB   (O_BOXES + BB*TOPKN*4)          // 38400
#define O_TIA    (O_PROB + (size_t)BB*TOPKN*CC)  // 7737600
#define O_BNORM  (O_TIA + BB*KSEL)               // 7801600

__device__ __forceinline__ uint32_t fkey(float f) {
    uint32_t x = __float_as_uint(f);
    return x ^ ((x & 0x80000000u) ? 0xFFFFFFFFu : 0x80000000u);
}
__device__ __forceinline__ float finv(uint32_t u) {
    uint32_t x = (u & 0x80000000u) ? (u ^ 0x80000000u) : ~u;
    return __uint_as_float(x);
}
__device__ __forceinline__ float sigmoidf_(float x) {
    if (x >= 0.0f) { float e = expf(-x); return 1.0f / (1.0f + e); }
    float e = expf(x); return e / (1.0f + e);
}

// ---------------- pass 1: single-pass speculative stash, contiguous chunk/block --------
__device__ __forceinline__ void stash_elem(float val, uint32_t idx,
                                           uint32_t* lcnt, uint64_t* lbuf) {
    uint64_t pk = ((uint64_t)fkey(val) << 32) | (uint32_t)(~idx);
    uint32_t pos = atomicAdd(lcnt, 1u);
    if (pos < SLICE) lbuf[pos] = pk;
}
__device__ __forceinline__ void stash_vec(float4 v, int i4,
                                          uint32_t* lcnt, uint64_t* lbuf) {
    float m = fmaxf(fmaxf(v.x, v.y), fmaxf(v.z, v.w));
    if (m >= SPEC_VAL) {                       // one branch per 4 elems; body is rare
        if (v.x >= SPEC_VAL) stash_elem(v.x, (uint32_t)(i4 * 4 + 0), lcnt, lbuf);
        if (v.y >= SPEC_VAL) stash_elem(v.y, (uint32_t)(i4 * 4 + 1), lcnt, lbuf);
        if (v.z >= SPEC_VAL) stash_elem(v.z, (uint32_t)(i4 * 4 + 2), lcnt, lbuf);
        if (v.w >= SPEC_VAL) stash_elem(v.w, (uint32_t)(i4 * 4 + 3), lcnt, lbuf);
    }
}

__global__ void __launch_bounds__(256) k_stash(const float4* __restrict__ lg4,
                                               uint32_t* __restrict__ bcnt,
                                               uint64_t* __restrict__ cand) {
    __shared__ uint64_t lbuf[SLICE];
    __shared__ uint32_t lcnt;
    const int b = blockIdx.y;
    const int blk = blockIdx.x;
    const int tid = threadIdx.x;
    if (tid == 0) lcnt = 0;
    __syncthreads();
    const float4* row = lg4 + (size_t)b * NROW4;
    const int start = blk * CHUNK;
    const int end = (start + CHUNK < NROW4) ? (start + CHUNK) : NROW4;

    int i = start + tid;
    // 8 independent float4 loads in flight per thread (128 B outstanding)
    for (; i + 1792 < end; i += 2048) {
        float4 v0 = row[i];
        float4 v1 = row[i + 256];
        float4 v2 = row[i + 512];
        float4 v3 = row[i + 768];
        float4 v4 = row[i + 1024];
        float4 v5 = row[i + 1280];
        float4 v6 = row[i + 1536];
        float4 v7 = row[i + 1792];
        stash_vec(v0, i,        &lcnt, lbuf);
        stash_vec(v1, i + 256,  &lcnt, lbuf);
        stash_vec(v2, i + 512,  &lcnt, lbuf);
        stash_vec(v3, i + 768,  &lcnt, lbuf);
        stash_vec(v4, i + 1024, &lcnt, lbuf);
        stash_vec(v5, i + 1280, &lcnt, lbuf);
        stash_vec(v6, i + 1536, &lcnt, lbuf);
        stash_vec(v7, i + 1792, &lcnt, lbuf);
    }
    for (; i < end; i += 256) {
        float4 v = row[i];
        stash_vec(v, i, &lcnt, lbuf);
    }
    __syncthreads();
    const uint32_t c = lcnt;
    uint64_t* slice = cand + ((size_t)b * GRIDX + blk) * SLICE;
    uint32_t n = (c < SLICE) ? c : SLICE;
    for (uint32_t i2 = tid; i2 < n; i2 += 256) slice[i2] = lbuf[i2];
    if (tid == 0) bcnt[b * GRIDX + blk] = c;   // overwrite (deterministic, no init needed)
}

// ---------------- pass 2: compact + sort + outputs; in-block exact fallback ----------------
__global__ void __launch_bounds__(1024) k_sortout(const float4* __restrict__ lg4,
                                                  const uint32_t* __restrict__ bcnt,
                                                  const uint64_t* __restrict__ cand,
                                                  const float4* __restrict__ pb4,
                                                  const float* __restrict__ tsz,
                                                  float* __restrict__ out,
                                                  int* __restrict__ qsel) {
    __shared__ uint64_t s[CAPN];          // 32 KiB; aliased as uint32 hist in fallback
    __shared__ uint32_t csum[1024];
    __shared__ uint32_t scnt[GRIDX], soff[GRIDX + 1];
    __shared__ int sh_valid;
    __shared__ uint32_t sh_n;
    __shared__ int sh_t;
    const int b = blockIdx.x;
    const int tid = threadIdx.x;
    const uint64_t* pcand = cand + (size_t)b * CAPN;
    uint32_t n;

    if (tid == 0) {
        uint32_t acc = 0;
        int ok = 1;
        for (int k = 0; k < GRIDX; ++k) {
            uint32_t c = bcnt[b * GRIDX + k];
            if (c > SLICE) ok = 0;
            scnt[k] = (c < SLICE) ? c : SLICE;
            soff[k] = acc;
            acc += scnt[k];
        }
        soff[GRIDX] = acc;
        sh_valid = ok && acc >= (uint32_t)KSEL;
    }
    __syncthreads();

    if (sh_valid) {
        n = soff[GRIDX];
        // 16 slices per pass, 4 passes (tid>>6 in 0..15, idx = tid&63)
#pragma unroll
        for (int p = 0; p < 4; ++p) {
            int k = p * 16 + (tid >> 6);
            int idx = tid & 63;
            if ((uint32_t)idx < scnt[k]) s[soff[k] + idx] = pcand[k * SLICE + idx];
        }
    } else {
        // ---- fallback: exact per-row selection, fully in-block (never taken for sane data) ----
        uint32_t* hs = (uint32_t*)s;
        for (int i = tid; i < NBINS; i += 1024) hs[i] = 0;
        __syncthreads();
        const float4* row = lg4 + (size_t)b * NROW4;
        for (int i = tid; i < NROW4; i += 1024) {
            float4 v = row[i];
            atomicAdd(&hs[fkey(v.x) >> 19], 1u);
            atomicAdd(&hs[fkey(v.y) >> 19], 1u);
            atomicAdd(&hs[fkey(v.z) >> 19], 1u);
            atomicAdd(&hs[fkey(v.w) >> 19], 1u);
        }
        __syncthreads();
        const int base = tid * 8;
        uint32_t ssum = 0;
#pragma unroll
        for (int k = 0; k < 8; ++k) ssum += hs[base + k];
        csum[tid] = ssum;
        __syncthreads();
        for (int off = 1; off < 1024; off <<= 1) {
            uint32_t v = csum[tid];
            uint32_t a = (tid + off < 1024) ? csum[tid + off] : 0u;
            __syncthreads();
            csum[tid] = v + a;
            __syncthreads();
        }
        if (csum[tid] >= KSEL && (tid == 1023 || csum[tid + 1] < KSEL)) {
            uint32_t acc = (tid == 1023) ? 0u : csum[tid + 1];
            int t = base;
            for (int k = 7; k >= 0; --k) {
                acc += hs[base + k];
                if (acc >= KSEL) { t = base + k; break; }
            }
            sh_t = t;
        }
        if (tid == 0) sh_n = 0;
        __syncthreads();
        const uint32_t ts = (uint32_t)sh_t;   // after this barrier nobody reads hs again
        for (int i = tid; i < NROW4; i += 1024) {
            float4 v = row[i];
            float c4[4] = {v.x, v.y, v.z, v.w};
#pragma unroll
            for (int j = 0; j < 4; ++j) {
                uint32_t u = fkey(c4[j]);
                if ((u >> 19) >= ts) {
                    uint32_t pos = atomicAdd(&sh_n, 1u);
                    if (pos < CAPN)
                        s[pos] = ((uint64_t)u << 32) | (uint32_t)(~(uint32_t)(i * 4 + j));
                }
            }
        }
        __syncthreads();
        n = sh_n;
    }
    if (n > CAPN) n = CAPN;
    const unsigned cap = (n <= 2048u) ? 2048u : 4096u;
    for (unsigned i = n + tid; i < cap; i += 1024) s[i] = 0ull;
    __syncthreads();

    // bitonic sort, descending composite (key desc, idx asc on ties)
    // direct pair indexing: exactly cap/2 compare-exchanges per step, no idle pass
    for (unsigned k = 2; k <= cap; k <<= 1) {
        for (unsigned j = k >> 1; j > 0; j >>= 1) {
            for (unsigned w = tid; w < (cap >> 1); w += 1024) {
                unsigned i = ((w & ~(j - 1)) << 1) | (w & (j - 1));
                unsigned ixj = i | j;
                uint64_t a = s[i], c = s[ixj];
                bool up = ((i & k) == 0);
                if (up ? (a < c) : (a > c)) { s[i] = c; s[ixj] = a; }
            }
            __syncthreads();
        }
    }

    for (int jj = tid; jj < KSEL; jj += 1024) {
        uint64_t c = s[jj];
        uint32_t idx = ~((uint32_t)c);
        uint32_t q = idx / (uint32_t)CC;
        out[O_TIA + b * KSEL + jj] = (float)q;
    }
    if (tid < TOPKN) {
        uint64_t c = s[tid];
        uint32_t u = (uint32_t)(c >> 32);
        uint32_t idx = ~((uint32_t)c);
        uint32_t q = idx / (uint32_t)CC;
        uint32_t lab = idx - q * (uint32_t)CC;
        float logit = finv(u);
        out[O_SCORES + b * TOPKN + tid] = sigmoidf_(logit);
        out[O_LABELS + b * TOPKN + tid] = (float)lab;
        qsel[b * TOPKN + tid] = (int)q;
        float4 pb = pb4[b * QQ + q];
        float x0 = pb.x - 0.5f * pb.z;
        float y0 = pb.y - 0.5f * pb.w;
        float x1 = pb.x + 0.5f * pb.z;
        float y1 = pb.y + 0.5f * pb.w;
        float ih = tsz[b * 2 + 0];
        float iw = tsz[b * 2 + 1];
        float4* obn = (float4*)(out + O_BNORM);
        float4* obx = (float4*)(out + O_BOXES);
        obn[b * TOPKN + tid] = make_float4(x0, y0, x1, y1);
        obx[b * TOPKN + tid] = make_float4(x0 * iw, y0 * ih, x1 * iw, y1 * ih);
    }
}

// ---------------- pass 3: topk_inst_prob gather + sigmoid (batched loads) ----------------
__global__ void __launch_bounds__(256) k_prob(const float* __restrict__ lg,
                                              const int* __restrict__ qsel,
                                              float* __restrict__ out) {
    const int r = blockIdx.x;          // 0..B*TOPK
    const int b = r / TOPKN;
    const int q = qsel[r];
    const int tid = threadIdx.x;
    const float* src = lg + ((size_t)b * QQ + q) * CC;
    float* dst = out + O_PROB + (size_t)r * CC;
    // CC = 1203 = 4*256 + 179: issue all 5 loads before any sigmoid
    float v0 = src[tid];
    float v1 = src[tid + 256];
    float v2 = src[tid + 512];
    float v3 = src[tid + 768];
    float v4 = (tid < CC - 1024) ? src[tid + 1024] : 0.0f;
    dst[tid]        = sigmoidf_(v0);
    dst[tid + 256]  = sigmoidf_(v1);
    dst[tid + 512]  = sigmoidf_(v2);
    dst[tid + 768]  = sigmoidf_(v3);
    if (tid < CC - 1024) dst[tid + 1024] = sigmoidf_(v4);
}

extern "C" void kernel_launch(void* const* d_in, const int* in_sizes, int n_in,
                              void* d_out, int out_size, void* d_ws, size_t ws_size,
                              hipStream_t stream) {
    const float* logits = (const float*)d_in[0];
    const float* boxes  = (const float*)d_in[1];
    const float* tsz    = (const float*)d_in[2];
    float* out = (float*)d_out;
    uint8_t* ws = (uint8_t*)d_ws;

    uint32_t* bcnt = (uint32_t*)(ws + WS_BCNT);
    uint64_t* cand = (uint64_t*)(ws + WS_CAND);
    int*      qsel = (int*)(ws + WS_QSEL);

    dim3 gs(GRIDX, BB);
    k_stash<<<gs, 256, 0, stream>>>((const float4*)logits, bcnt, cand);
    k_sortout<<<BB, 1024, 0, stream>>>((const float4*)logits, bcnt, cand,
                                       (const float4*)boxes, tsz, out, qsel);
    k_prob<<<BB * TOPKN, 256, 0, stream>>>(logits, qsel, out);
}

// Round 8
// 92.217 us; speedup vs baseline: 5.6028x; 1.0143x over previous
//
#include <hip/hip_runtime.h>
#include <stdint.h>

#define BB   64
#define QQ   1000
#define CC   1203
#define NROW (QQ*CC)         // 1203000
#define NROW4 (NROW/4)       // 300750
#define KSEL 1000
#define TOPKN 100
#define NBINS 8192
#define CAPN 4096
#define SLICE 64             // cand slots per (row, chunk); 64 * 64 = 4096 = CAPN
#define GRIDX 64             // == wavefront size: bcnt scan fits one wave
#define CHUNK ((NROW4 + GRIDX - 1) / GRIDX)   // 4700 float4 per block, contiguous
#define SPEC_VAL 3.0f        // row mean 1624 (15 sigma > 1000); chunk mean 25.4 (7.9 sigma < 64)

// workspace byte offsets (no zeroing needed: every word read is overwritten first)
#define WS_BCNT  0                                   // BB*GRIDX*4 = 16384 B
#define WS_CAND  (BB*GRIDX*4)
#define WS_QSEL  (WS_CAND + (size_t)BB*CAPN*8)

// output float offsets (return-order concat)
#define O_SCORES 0
#define O_LABELS (BB*TOPKN)                      // 6400
#define O_BOXES  (2*BB*TOPKN)                    // 12800
#define O_PROB   (O_BOXES + BB*TOPKN*4)          // 38400
#define O_TIA    (O_PROB + (size_t)BB*TOPKN*CC)  // 7737600
#define O_BNORM  (O_TIA + BB*KSEL)               // 7801600

__device__ __forceinline__ uint32_t fkey(float f) {
    uint32_t x = __float_as_uint(f);
    return x ^ ((x & 0x80000000u) ? 0xFFFFFFFFu : 0x80000000u);
}
__device__ __forceinline__ float finv(uint32_t u) {
    uint32_t x = (u & 0x80000000u) ? (u ^ 0x80000000u) : ~u;
    return __uint_as_float(x);
}
__device__ __forceinline__ float sigmoidf_(float x) {
    if (x >= 0.0f) { float e = expf(-x); return 1.0f / (1.0f + e); }
    float e = expf(x); return e / (1.0f + e);
}

// ---------------- pass 1: single-pass speculative stash, contiguous chunk/block --------
__device__ __forceinline__ void stash_elem(float val, uint32_t idx,
                                           uint32_t* lcnt, uint64_t* lbuf) {
    uint64_t pk = ((uint64_t)fkey(val) << 32) | (uint32_t)(~idx);
    uint32_t pos = atomicAdd(lcnt, 1u);
    if (pos < SLICE) lbuf[pos] = pk;
}
__device__ __forceinline__ void stash_vec(float4 v, int i4,
                                          uint32_t* lcnt, uint64_t* lbuf) {
    float m = fmaxf(fmaxf(v.x, v.y), fmaxf(v.z, v.w));
    if (m >= SPEC_VAL) {                       // one branch per 4 elems; body is rare
        if (v.x >= SPEC_VAL) stash_elem(v.x, (uint32_t)(i4 * 4 + 0), lcnt, lbuf);
        if (v.y >= SPEC_VAL) stash_elem(v.y, (uint32_t)(i4 * 4 + 1), lcnt, lbuf);
        if (v.z >= SPEC_VAL) stash_elem(v.z, (uint32_t)(i4 * 4 + 2), lcnt, lbuf);
        if (v.w >= SPEC_VAL) stash_elem(v.w, (uint32_t)(i4 * 4 + 3), lcnt, lbuf);
    }
}

__global__ void __launch_bounds__(256) k_stash(const float4* __restrict__ lg4,
                                               uint32_t* __restrict__ bcnt,
                                               uint64_t* __restrict__ cand) {
    __shared__ uint64_t lbuf[SLICE];
    __shared__ uint32_t lcnt;
    const int b = blockIdx.y;
    const int blk = blockIdx.x;
    const int tid = threadIdx.x;
    if (tid == 0) lcnt = 0;
    __syncthreads();
    const float4* row = lg4 + (size_t)b * NROW4;
    const int start = blk * CHUNK;
    const int end = (start + CHUNK < NROW4) ? (start + CHUNK) : NROW4;

    int i = start + tid;
    // 8 independent float4 loads in flight per thread (128 B outstanding)
    for (; i + 1792 < end; i += 2048) {
        float4 v0 = row[i];
        float4 v1 = row[i + 256];
        float4 v2 = row[i + 512];
        float4 v3 = row[i + 768];
        float4 v4 = row[i + 1024];
        float4 v5 = row[i + 1280];
        float4 v6 = row[i + 1536];
        float4 v7 = row[i + 1792];
        stash_vec(v0, i,        &lcnt, lbuf);
        stash_vec(v1, i + 256,  &lcnt, lbuf);
        stash_vec(v2, i + 512,  &lcnt, lbuf);
        stash_vec(v3, i + 768,  &lcnt, lbuf);
        stash_vec(v4, i + 1024, &lcnt, lbuf);
        stash_vec(v5, i + 1280, &lcnt, lbuf);
        stash_vec(v6, i + 1536, &lcnt, lbuf);
        stash_vec(v7, i + 1792, &lcnt, lbuf);
    }
    for (; i < end; i += 256) {
        float4 v = row[i];
        stash_vec(v, i, &lcnt, lbuf);
    }
    __syncthreads();
    const uint32_t c = lcnt;
    uint64_t* slice = cand + ((size_t)b * GRIDX + blk) * SLICE;
    uint32_t n = (c < SLICE) ? c : SLICE;
    for (uint32_t i2 = tid; i2 < n; i2 += 256) slice[i2] = lbuf[i2];
    if (tid == 0) bcnt[b * GRIDX + blk] = c;   // overwrite (deterministic, no init needed)
}

// ---------------- pass 2: compact + sort + outputs; in-block exact fallback ----------------
__global__ void __launch_bounds__(1024) k_sortout(const float4* __restrict__ lg4,
                                                  const uint32_t* __restrict__ bcnt,
                                                  const uint64_t* __restrict__ cand,
                                                  const float4* __restrict__ pb4,
                                                  const float* __restrict__ tsz,
                                                  float* __restrict__ out,
                                                  int* __restrict__ qsel) {
    __shared__ uint64_t s[CAPN];          // 32 KiB; aliased as uint32 hist in fallback
    __shared__ uint32_t csum[1024];
    __shared__ uint32_t scnt[GRIDX], soff[GRIDX + 1];
    __shared__ int sh_valid;
    __shared__ uint32_t sh_n;
    __shared__ int sh_t;
    const int b = blockIdx.x;
    const int tid = threadIdx.x;
    const uint64_t* pcand = cand + (size_t)b * CAPN;
    uint32_t n;

    // wave-parallel bcnt scan: one coalesced 256B load + ballot + shfl_up prefix scan
    if (tid < GRIDX) {                      // GRIDX == 64 == one full wave
        uint32_t c = bcnt[b * GRIDX + tid];
        unsigned long long bad = __ballot(c > SLICE);
        uint32_t cc = (c < SLICE) ? c : SLICE;
        uint32_t inc = cc;
#pragma unroll
        for (int off = 1; off < 64; off <<= 1) {
            uint32_t up = __shfl_up(inc, off, 64);
            if (tid >= off) inc += up;
        }
        scnt[tid] = cc;
        soff[tid] = inc - cc;               // exclusive prefix
        if (tid == GRIDX - 1) {
            soff[GRIDX] = inc;              // total
            sh_valid = (bad == 0ull) && inc >= (uint32_t)KSEL;
        }
    }
    __syncthreads();

    if (sh_valid) {
        n = soff[GRIDX];
        // 16 slices per pass, 4 passes (tid>>6 in 0..15, idx = tid&63)
#pragma unroll
        for (int p = 0; p < 4; ++p) {
            int k = p * 16 + (tid >> 6);
            int idx = tid & 63;
            if ((uint32_t)idx < scnt[k]) s[soff[k] + idx] = pcand[k * SLICE + idx];
        }
    } else {
        // ---- fallback: exact per-row selection, fully in-block (never taken for sane data) ----
        uint32_t* hs = (uint32_t*)s;
        for (int i = tid; i < NBINS; i += 1024) hs[i] = 0;
        __syncthreads();
        const float4* row = lg4 + (size_t)b * NROW4;
        for (int i = tid; i < NROW4; i += 1024) {
            float4 v = row[i];
            atomicAdd(&hs[fkey(v.x) >> 19], 1u);
            atomicAdd(&hs[fkey(v.y) >> 19], 1u);
            atomicAdd(&hs[fkey(v.z) >> 19], 1u);
            atomicAdd(&hs[fkey(v.w) >> 19], 1u);
        }
        __syncthreads();
        const int base = tid * 8;
        uint32_t ssum = 0;
#pragma unroll
        for (int k = 0; k < 8; ++k) ssum += hs[base + k];
        csum[tid] = ssum;
        __syncthreads();
        for (int off = 1; off < 1024; off <<= 1) {
            uint32_t v = csum[tid];
            uint32_t a = (tid + off < 1024) ? csum[tid + off] : 0u;
            __syncthreads();
            csum[tid] = v + a;
            __syncthreads();
        }
        if (csum[tid] >= KSEL && (tid == 1023 || csum[tid + 1] < KSEL)) {
            uint32_t acc = (tid == 1023) ? 0u : csum[tid + 1];
            int t = base;
            for (int k = 7; k >= 0; --k) {
                acc += hs[base + k];
                if (acc >= KSEL) { t = base + k; break; }
            }
            sh_t = t;
        }
        if (tid == 0) sh_n = 0;
        __syncthreads();
        const uint32_t ts = (uint32_t)sh_t;   // after this barrier nobody reads hs again
        for (int i = tid; i < NROW4; i += 1024) {
            float4 v = row[i];
            float c4[4] = {v.x, v.y, v.z, v.w};
#pragma unroll
            for (int j = 0; j < 4; ++j) {
                uint32_t u = fkey(c4[j]);
                if ((u >> 19) >= ts) {
                    uint32_t pos = atomicAdd(&sh_n, 1u);
                    if (pos < CAPN)
                        s[pos] = ((uint64_t)u << 32) | (uint32_t)(~(uint32_t)(i * 4 + j));
                }
            }
        }
        __syncthreads();
        n = sh_n;
    }
    if (n > CAPN) n = CAPN;
    const unsigned cap = (n <= 2048u) ? 2048u : 4096u;
    for (unsigned i = n + tid; i < cap; i += 1024) s[i] = 0ull;
    __syncthreads();

    // bitonic sort, descending composite (key desc, idx asc on ties)
    // direct pair indexing: exactly cap/2 compare-exchanges per step, no idle pass
    for (unsigned k = 2; k <= cap; k <<= 1) {
        for (unsigned j = k >> 1; j > 0; j >>= 1) {
            for (unsigned w = tid; w < (cap >> 1); w += 1024) {
                unsigned i = ((w & ~(j - 1)) << 1) | (w & (j - 1));
                unsigned ixj = i | j;
                uint64_t a = s[i], c = s[ixj];
                bool up = ((i & k) == 0);
                if (up ? (a < c) : (a > c)) { s[i] = c; s[ixj] = a; }
            }
            __syncthreads();
        }
    }

    for (int jj = tid; jj < KSEL; jj += 1024) {
        uint64_t c = s[jj];
        uint32_t idx = ~((uint32_t)c);
        uint32_t q = idx / (uint32_t)CC;
        out[O_TIA + b * KSEL + jj] = (float)q;
    }
    if (tid < TOPKN) {
        uint64_t c = s[tid];
        uint32_t u = (uint32_t)(c >> 32);
        uint32_t idx = ~((uint32_t)c);
        uint32_t q = idx / (uint32_t)CC;
        uint32_t lab = idx - q * (uint32_t)CC;
        float logit = finv(u);
        out[O_SCORES + b * TOPKN + tid] = sigmoidf_(logit);
        out[O_LABELS + b * TOPKN + tid] = (float)lab;
        qsel[b * TOPKN + tid] = (int)q;
        float4 pb = pb4[b * QQ + q];
        float x0 = pb.x - 0.5f * pb.z;
        float y0 = pb.y - 0.5f * pb.w;
        float x1 = pb.x + 0.5f * pb.z;
        float y1 = pb.y + 0.5f * pb.w;
        float ih = tsz[b * 2 + 0];
        float iw = tsz[b * 2 + 1];
        float4* obn = (float4*)(out + O_BNORM);
        float4* obx = (float4*)(out + O_BOXES);
        obn[b * TOPKN + tid] = make_float4(x0, y0, x1, y1);
        obx[b * TOPKN + tid] = make_float4(x0 * iw, y0 * ih, x1 * iw, y1 * ih);
    }
}

// ---------------- pass 3: topk_inst_prob gather + sigmoid (batched loads) ----------------
__global__ void __launch_bounds__(256) k_prob(const float* __restrict__ lg,
                                              const int* __restrict__ qsel,
                                              float* __restrict__ out) {
    const int r = blockIdx.x;          // 0..B*TOPK
    const int b = r / TOPKN;
    const int q = qsel[r];
    const int tid = threadIdx.x;
    const float* src = lg + ((size_t)b * QQ + q) * CC;
    float* dst = out + O_PROB + (size_t)r * CC;
    // CC = 1203 = 4*256 + 179: issue all 5 loads before any sigmoid
    float v0 = src[tid];
    float v1 = src[tid + 256];
    float v2 = src[tid + 512];
    float v3 = src[tid + 768];
    float v4 = (tid < CC - 1024) ? src[tid + 1024] : 0.0f;
    dst[tid]        = sigmoidf_(v0);
    dst[tid + 256]  = sigmoidf_(v1);
    dst[tid + 512]  = sigmoidf_(v2);
    dst[tid + 768]  = sigmoidf_(v3);
    if (tid < CC - 1024) dst[tid + 1024] = sigmoidf_(v4);
}

extern "C" void kernel_launch(void* const* d_in, const int* in_sizes, int n_in,
                              void* d_out, int out_size, void* d_ws, size_t ws_size,
                              hipStream_t stream) {
    const float* logits = (const float*)d_in[0];
    const float* boxes  = (const float*)d_in[1];
    const float* tsz    = (const float*)d_in[2];
    float* out = (float*)d_out;
    uint8_t* ws = (uint8_t*)d_ws;

    uint32_t* bcnt = (uint32_t*)(ws + WS_BCNT);
    uint64_t* cand = (uint64_t*)(ws + WS_CAND);
    int*      qsel = (int*)(ws + WS_QSEL);

    dim3 gs(GRIDX, BB);
    k_stash<<<gs, 256, 0, stream>>>((const float4*)logits, bcnt, cand);
    k_sortout<<<BB, 1024, 0, stream>>>((const float4*)logits, bcnt, cand,
                                       (const float4*)boxes, tsz, out, qsel);
    k_prob<<<BB * TOPKN, 256, 0, stream>>>(logits, qsel, out);
}